// Round 8
// baseline (187.539 us; speedup 1.0000x reference)
//
#include <hip/hip_runtime.h>
#include <hip/hip_bf16.h>
#include <math.h>
#include <type_traits>

#define D_MODEL 1024
#define NHEADS  16
#define DK      64
#define SEQ     2048
#define BATCH   2
#define QTILE   256

typedef __attribute__((ext_vector_type(8)))  short  short8;
typedef __attribute__((ext_vector_type(8)))  unsigned short ushort8;
typedef __attribute__((ext_vector_type(4)))  float  floatx4;
typedef __attribute__((ext_vector_type(16))) float  floatx16;

template <int N> using IC = std::integral_constant<int, N>;

__device__ __forceinline__ unsigned short f2bf(float f) {      // RNE
    union { float f; unsigned int u; } v; v.f = f;
    unsigned int u = v.u;
    return (unsigned short)((u + 0x7FFFu + ((u >> 16) & 1u)) >> 16);
}
__device__ __forceinline__ float bf2f(unsigned short u) {
    union { unsigned int u; float f; } v; v.u = ((unsigned int)u) << 16;
    return v.f;
}
__device__ __forceinline__ unsigned int fau(float f) {
    union { float f; unsigned int u; } v; v.f = f; return v.u;
}

// async global->LDS, 16B per lane. LDS dest = wave-uniform base + lane*16.
__device__ __forceinline__ void gload_lds16(const unsigned short* g, unsigned short* l) {
    __builtin_amdgcn_global_load_lds((__attribute__((address_space(1))) const void*)g,
                                     (__attribute__((address_space(3))) void*)l,
                                     16, 0, 0);
}

// ---------------- fused fp32 -> bf16 pack of x, w_qkv, w_out ----------------
#define X8 ((BATCH * SEQ * D_MODEL) / 8)
#define W8 ((3 * D_MODEL * D_MODEL) / 8)
#define O8 ((D_MODEL * D_MODEL) / 8)
__global__ __launch_bounds__(256) void pack_all(const float* __restrict__ x,
                                                const float* __restrict__ wq,
                                                const float* __restrict__ wo,
                                                unsigned short* __restrict__ xb,
                                                unsigned short* __restrict__ wqb,
                                                unsigned short* __restrict__ wob) {
    const int t = blockIdx.x * blockDim.x + threadIdx.x;
    const float* src; unsigned short* dst; int idx;
    if (t < X8)           { src = x;  dst = xb;  idx = t; }
    else if (t < X8 + W8) { src = wq; dst = wqb; idx = t - X8; }
    else if (t < X8 + W8 + O8) { src = wo; dst = wob; idx = t - X8 - W8; }
    else return;
    const float4 a = ((const float4*)src)[2 * idx];
    const float4 b = ((const float4*)src)[2 * idx + 1];
    short8 o;
    o[0] = (short)f2bf(a.x); o[1] = (short)f2bf(a.y);
    o[2] = (short)f2bf(a.z); o[3] = (short)f2bf(a.w);
    o[4] = (short)f2bf(b.x); o[5] = (short)f2bf(b.y);
    o[6] = (short)f2bf(b.z); o[7] = (short)f2bf(b.w);
    ((short8*)dst)[idx] = o;
}

// ---------------- QKV GEMM: 256x256 tile, BK=64, 8-phase counted-vmcnt pipeline ----
// Phase factorization (kk, mh): 8 ds_read_b128 + 16 MFMA per phase, 32 reads/K-tile.
// Staging order per tile: B0,B1,A0,A1 (2 gload each). Waits traced:
//   P0 vmcnt(2) drains B0,B1,A0(t); P1 vmcnt(2) drains A1(t); P2 vmcnt(4) no-op;
//   P3 vmcnt(4) drains B0(t+1) (3 phases old). Never drains to 0.
// T2 swizzle both-sides; T5 setprio; T1 XCD-contiguous block swizzle.
#define QKV_M 4096
#define QKV_N 3072
#define QKV_K 1024
#define QKV_NT (QKV_K / 64)

__global__ __launch_bounds__(512, 2) void gemm_qkv_8ph(const unsigned short* __restrict__ A,
                                                        const unsigned short* __restrict__ B,
                                                        unsigned short* __restrict__ C) {
    __shared__ __align__(16) unsigned short As[2][256][64];   // 64 KB
    __shared__ __align__(16) unsigned short Bs[2][256][64];   // 64 KB

    const int tid  = threadIdx.x;
    const int w    = tid >> 6;        // wave 0..7
    const int lane = tid & 63;
    const int quad = lane >> 4;
    const int lcol = lane & 15;
    const int wr   = w >> 2;          // 0..1  (M half: 128 rows)
    const int wc   = w & 3;           // 0..3  (N quarter: 64 cols)

    // XCD-contiguous swizzle: 192 blocks = 8 XCDs x 24
    const int f  = blockIdx.x;
    const int wg = (f & 7) * 24 + (f >> 3);
    const int tn = (wg % (QKV_N / 256)) * 256;
    const int tm = (wg / (QKV_N / 256)) * 256;

    const int srow8 = lane >> 3;      // staging: row within 8-row block
    const int sj    = lane & 7;       // staging: 16B chunk within row

    // stage A-group mh (rows {mh*64..+64} u {128+mh*64..+64}) of K-tile kt into buf
    auto stageA = [&](int buf, int kt, int mh) {
#pragma unroll
        for (int c = 0; c < 2; ++c) {
            const int r0 = mh * 64 + c * 128 + w * 8;
            const int r  = r0 + srow8;
            gload_lds16(A + (size_t)(tm + r) * QKV_K + kt * 64 + ((sj ^ (r & 7)) * 8),
                        &As[buf][r0][0]);
        }
    };
    // stage B-group nh (rows {k*64 + nh*32 .. +32 : k=0..3}) of K-tile kt into buf
    auto stageB = [&](int buf, int kt, int nh) {
#pragma unroll
        for (int c = 0; c < 2; ++c) {
            const int rho0 = c * 64 + w * 8;
            const int r0   = (rho0 >> 5) * 64 + nh * 32 + (rho0 & 31);
            const int r    = r0 + srow8;
            gload_lds16(B + (size_t)(tn + r) * QKV_K + kt * 64 + ((sj ^ (r & 7)) * 8),
                        &Bs[buf][r0][0]);
        }
    };

    floatx4 acc[8][4];
#pragma unroll
    for (int i = 0; i < 8; ++i)
#pragma unroll
        for (int j = 0; j < 4; ++j) acc[i][j] = (floatx4){0.f, 0.f, 0.f, 0.f};

    // phase (kk, mh): A-half x all-B at k-slice kk; 8 ds_read_b128 + 16 MFMA
    auto do_phase = [&](int buf, auto vmc, auto kkc, auto mhc, auto stager) {
        constexpr int VM = decltype(vmc)::value;
        constexpr int kk = decltype(kkc)::value;
        constexpr int mh = decltype(mhc)::value;
        if constexpr (VM == 2) asm volatile("s_waitcnt vmcnt(2)" ::: "memory");
        else                   asm volatile("s_waitcnt vmcnt(4)" ::: "memory");
        __builtin_amdgcn_s_barrier();
        asm volatile("" ::: "memory");          // no LDS reads above the barrier
        short8 a[4], b[4];
#pragma unroll
        for (int i = 0; i < 4; ++i) {
            const int r = wr * 128 + mh * 64 + i * 16 + lcol;
            a[i] = *(const short8*)&As[buf][r][((kk * 4 + quad) ^ (r & 7)) * 8];
        }
#pragma unroll
        for (int j = 0; j < 4; ++j) {
            const int r = wc * 64 + j * 16 + lcol;
            b[j] = *(const short8*)&Bs[buf][r][((kk * 4 + quad) ^ (r & 7)) * 8];
        }
        stager();
        __builtin_amdgcn_s_setprio(1);
#pragma unroll
        for (int i = 0; i < 4; ++i)
#pragma unroll
            for (int j = 0; j < 4; ++j)
                acc[mh * 4 + i][j] = __builtin_amdgcn_mfma_f32_16x16x32_bf16(
                    a[i], b[j], acc[mh * 4 + i][j], 0, 0, 0);
        __builtin_amdgcn_s_setprio(0);
    };

    // prologue: tile 0 -> buf 0, staging order B0 B1 A0 A1
    stageB(0, 0, 0); stageB(0, 0, 1); stageA(0, 0, 0); stageA(0, 0, 1);

    for (int t = 0; t < QKV_NT; ++t) {
        const int buf = t & 1, nb = buf ^ 1;
        const int kn = (t + 1 == QKV_NT) ? 0 : t + 1;   // wrap: dead restage keeps invariant
        do_phase(buf, IC<2>{}, IC<0>{}, IC<0>{}, [&] { stageB(nb, kn, 0); });
        do_phase(buf, IC<2>{}, IC<0>{}, IC<1>{}, [&] { stageB(nb, kn, 1); });
        do_phase(buf, IC<4>{}, IC<1>{}, IC<0>{}, [&] { stageA(nb, kn, 0); });
        do_phase(buf, IC<4>{}, IC<1>{}, IC<1>{}, [&] { stageA(nb, kn, 1); });
    }

    // epilogue: C-write (bf16)
#pragma unroll
    for (int i = 0; i < 8; ++i) {
#pragma unroll
        for (int rr = 0; rr < 4; ++rr) {
            const int row = tm + wr * 128 + i * 16 + quad * 4 + rr;
#pragma unroll
            for (int jf = 0; jf < 4; ++jf) {
                const int col = tn + wc * 64 + jf * 16 + lcol;
                C[(size_t)row * QKV_N + col] = f2bf(acc[i][jf][rr]);
            }
        }
    }
}

// ---------------- out-proj GEMM: 128x128 tile, BK=64, 8-phase counted-vmcnt ----------
#define OUT_M 4096
#define OUT_N 1024
#define OUT_K 1024
#define OUT_NT (OUT_K / 64)

__global__ __launch_bounds__(512, 2) void gemm_out_8ph(const unsigned short* __restrict__ A,
                                                       const unsigned short* __restrict__ B,
                                                       const float* __restrict__ bias,
                                                       float* __restrict__ C) {
    __shared__ __align__(16) unsigned short As[2][128][64];   // 32 KB
    __shared__ __align__(16) unsigned short Bs[2][128][64];   // 32 KB

    const int tid  = threadIdx.x;
    const int w    = tid >> 6;        // wave 0..7
    const int lane = tid & 63;
    const int quad = lane >> 4;
    const int lcol = lane & 15;
    const int wr   = w >> 2;          // 0..1  (M half: 64 rows)
    const int wc   = w & 3;           // 0..3  (N quarter: 32 cols)

    // XCD-contiguous swizzle: 256 blocks = 8 XCDs x 32
    const int f  = blockIdx.x;
    const int wg = (f & 7) * 32 + (f >> 3);
    const int tn = (wg & 7) * 128;    // OUT_N/128 = 8
    const int tm = (wg >> 3) * 128;   // OUT_M/128 = 32

    const int srow8 = lane >> 3;
    const int sj    = lane & 7;

    // A-group mh: rows {mh*32+[0,32)} u {64+mh*32+[0,32)}; 8 waves x 8 rows, 1 gload
    auto stageA = [&](int buf, int kt, int mh) {
        const int r0 = (w & 3) * 8 + mh * 32 + (w >> 2) * 64;
        const int r  = r0 + srow8;
        gload_lds16(A + (size_t)(tm + r) * OUT_K + kt * 64 + ((sj ^ (r & 7)) * 8),
                    &As[buf][r0][0]);
    };
    // B-group nh: rows {c*32 + nh*16 + [0,16) : c=0..3}; 8 waves x 8 rows, 1 gload
    auto stageB = [&](int buf, int kt, int nh) {
        const int r0 = (w >> 1) * 32 + nh * 16 + (w & 1) * 8;
        const int r  = r0 + srow8;
        gload_lds16(B + (size_t)(tn + r) * OUT_K + kt * 64 + ((sj ^ (r & 7)) * 8),
                    &Bs[buf][r0][0]);
    };

    floatx4 acc[4][2];
#pragma unroll
    for (int i = 0; i < 4; ++i)
#pragma unroll
        for (int j = 0; j < 2; ++j) acc[i][j] = (floatx4){0.f, 0.f, 0.f, 0.f};

    auto do_phase = [&](int buf, auto vmc, auto kkc, auto mhc, auto stager) {
        constexpr int VM = decltype(vmc)::value;
        constexpr int kk = decltype(kkc)::value;
        constexpr int mh = decltype(mhc)::value;
        if constexpr (VM == 1) asm volatile("s_waitcnt vmcnt(1)" ::: "memory");
        else                   asm volatile("s_waitcnt vmcnt(2)" ::: "memory");
        __builtin_amdgcn_s_barrier();
        asm volatile("" ::: "memory");          // no LDS reads above the barrier
        short8 a[2], b[2];
#pragma unroll
        for (int i = 0; i < 2; ++i) {
            const int r = wr * 64 + mh * 32 + i * 16 + lcol;
            a[i] = *(const short8*)&As[buf][r][((kk * 4 + quad) ^ (r & 7)) * 8];
        }
#pragma unroll
        for (int j = 0; j < 2; ++j) {
            const int r = wc * 32 + j * 16 + lcol;
            b[j] = *(const short8*)&Bs[buf][r][((kk * 4 + quad) ^ (r & 7)) * 8];
        }
        stager();
        __builtin_amdgcn_s_setprio(1);
#pragma unroll
        for (int i = 0; i < 2; ++i)
#pragma unroll
            for (int j = 0; j < 2; ++j)
                acc[mh * 2 + i][j] = __builtin_amdgcn_mfma_f32_16x16x32_bf16(
                    a[i], b[j], acc[mh * 2 + i][j], 0, 0, 0);
        __builtin_amdgcn_s_setprio(0);
    };

    // prologue: tile 0 -> buf 0, order B0 B1 A0 A1
    stageB(0, 0, 0); stageB(0, 0, 1); stageA(0, 0, 0); stageA(0, 0, 1);

    for (int t = 0; t < OUT_NT; ++t) {
        const int buf = t & 1, nb = buf ^ 1;
        const int kn = (t + 1 == OUT_NT) ? 0 : t + 1;   // wrap: dead restage keeps invariant
        do_phase(buf, IC<1>{}, IC<0>{}, IC<0>{}, [&] { stageB(nb, kn, 0); });
        do_phase(buf, IC<1>{}, IC<0>{}, IC<1>{}, [&] { stageB(nb, kn, 1); });
        do_phase(buf, IC<2>{}, IC<1>{}, IC<0>{}, [&] { stageA(nb, kn, 0); });
        do_phase(buf, IC<2>{}, IC<1>{}, IC<1>{}, [&] { stageA(nb, kn, 1); });
    }

    // epilogue: fp32 C-write + bias
#pragma unroll
    for (int i = 0; i < 4; ++i) {
#pragma unroll
        for (int rr = 0; rr < 4; ++rr) {
            const int row = tm + wr * 64 + i * 16 + quad * 4 + rr;
#pragma unroll
            for (int j = 0; j < 2; ++j) {
                const int col = tn + wc * 32 + j * 16 + lcol;
                C[(size_t)row * OUT_N + col] = acc[i][j][rr] + bias[col];
            }
        }
    }
}

// ---------------- fused RoPE pack (Q*0.125*log2e, K) + sigma-permuted V transpose ---
// Key u within each 64-tile is stored at column c(u) = (u&48) | (8*((u>>2)&1) + (u&3)
// + 4*((u>>3)&1)) so PV's A-operand (= S^T C-regs) and B-operand (V) agree on the
// 32x32x16 MFMA k-index mapping.
__global__ __launch_bounds__(256) void rope_vtrans(const unsigned short* __restrict__ qkvb,
                                                   unsigned short* __restrict__ Qb,
                                                   unsigned short* __restrict__ Kb,
                                                   unsigned short* __restrict__ Vtg) {
    const int st = blockIdx.x, h = blockIdx.y, b = blockIdx.z;
    const int tid = threadIdx.x;
    const int s0 = st * 64;

    // ---- RoPE on Q,K ----
    const int i  = tid & 31;
    const int r0 = tid >> 5;                   // 0..7
    const float inv_freq = exp2f(-(2.0f * (float)i / (float)DK) * log2f(50.0f));
    const float QSCALE = 0.125f * 1.44269504f; // 1/sqrt(dk) * log2(e)
#pragma unroll
    for (int pass = 0; pass < 8; ++pass) {
        const int s = s0 + r0 + pass * 8;
        const size_t in_base = ((size_t)(b * SEQ + s)) * (3 * D_MODEL) + h * DK + 2 * i;
        const float q0 = bf2f(qkvb[in_base]),           q1 = bf2f(qkvb[in_base + 1]);
        const float k0 = bf2f(qkvb[in_base + D_MODEL]), k1 = bf2f(qkvb[in_base + D_MODEL + 1]);
        float sn, cs;
        __sincosf((float)s * inv_freq, &sn, &cs);
        const size_t ob = (((size_t)(b * NHEADS + h)) * SEQ + s) * DK + 2 * i;
        const unsigned int qw = (unsigned int)f2bf((q0 * cs - q1 * sn) * QSCALE)
                              | ((unsigned int)f2bf((q1 * cs + q0 * sn) * QSCALE) << 16);
        const unsigned int kw = (unsigned int)f2bf(k0 * cs - k1 * sn)
                              | ((unsigned int)f2bf(k1 * cs + k0 * sn) << 16);
        *(unsigned int*)&Qb[ob] = qw;
        *(unsigned int*)&Kb[ob] = kw;
    }

    // ---- V transpose with sigma column permutation ----
    __shared__ unsigned short Lt[64][65];
    const int r = tid >> 3;                    // 0..31 (key within tile)
    const int c = (tid & 7) * 8;
    const size_t in_row = ((size_t)(b * SEQ + s0 + r)) * (3 * D_MODEL) + 2 * D_MODEL + h * DK + c;
    const ushort8 v0 = *(const ushort8*)&qkvb[in_row];
    const ushort8 v1 = *(const ushort8*)&qkvb[in_row + (size_t)32 * (3 * D_MODEL)];
    const int u0 = r, u1 = r + 32;
    const int kc0 = (u0 & 48) | (8 * ((u0 >> 2) & 1) + (u0 & 3) + 4 * ((u0 >> 3) & 1));
    const int kc1 = (u1 & 48) | (8 * ((u1 >> 2) & 1) + (u1 & 3) + 4 * ((u1 >> 3) & 1));
#pragma unroll
    for (int j = 0; j < 8; ++j) Lt[c + j][kc0] = v0[j];
#pragma unroll
    for (int j = 0; j < 8; ++j) Lt[c + j][kc1] = v1[j];
    __syncthreads();
    const size_t bh = (size_t)(b * NHEADS + h);
    ushort8 o0, o1;
#pragma unroll
    for (int j = 0; j < 8; ++j) { o0[j] = Lt[r][c + j]; o1[j] = Lt[r + 32][c + j]; }
    unsigned short* orow = Vtg + (bh * DK + r) * SEQ + s0 + c;   // r = d-row
    *(ushort8*)orow = o0;
    *(ushort8*)(orow + (size_t)32 * SEQ) = o1;
}

// ---------------- flash attention: QTILE=256, async-staged, counted-vmcnt pipeline --
// r6 wave shape (8 waves x 32q x full 64k, wave-local shfl epilogue) with the GEMM-
// style T3+T4 staging: K/V tiles (8 KB each) staged via global_load_lds into a
// TRIPLE-buffered linear LDS [64][64] (XOR-chunk swizzle on global source AND ds_read,
// rule 21). Per tile: {vmcnt(2); s_barrier; issue tile j+2 (2 gloads); ds_reads;
// MFMA/exp/PV}. vmcnt(2) retires exactly tile j's K,V and leaves tile j+1 in flight —
// the main loop NEVER drains vmcnt to 0 (the old reg-staged __syncthreads did, every
// phase: that drain is the stall common to the r3/r6/r7 shapes all stuck at 44-48us).
// RAW: tile j staged 2 phases early (~2 phase-times >= L2 latency). WAR: buf[(j+2)%3]
// last read in phase j-1, reads complete before barrier j, issue is after barrier j.
__global__ __launch_bounds__(512, 2) void flash_attn(const unsigned short* __restrict__ Qb,
                                                     const unsigned short* __restrict__ Kb,
                                                     const unsigned short* __restrict__ Vtg,
                                                     unsigned short* __restrict__ attnb) {
    const int tid  = threadIdx.x;
    const int w8   = tid >> 6;                // wave 0..7 = q-subtile (32 rows)
    const int lane = tid & 63;
    const int l31  = lane & 31;
    const int lh   = lane >> 5;               // lane half (k-subgroup)

    // XCD-grouping swizzle: 256 blocks = 8 XCDs x 32; consecutive w share (b,h) -> K/V
    // (512 KB/bh) L2-resident per XCD.
    const int f  = blockIdx.x + gridDim.x * (blockIdx.y + gridDim.y * blockIdx.z);
    const int w  = (f & 7) * 32 + (f >> 3);   // bijective (256 % 8 == 0)
    const int qt = w & 7;                     // 0..7 (tiles of 256 queries)
    const int h  = (w >> 3) & 15;
    const int b  = w >> 7;

    __shared__ __align__(16) unsigned char smem[49152];   // 3 x (K 8192 + V 8192)

    const size_t bh = (size_t)(b * NHEADS + h);
    const unsigned short* Qg = Qb + (bh * SEQ + (size_t)qt * QTILE) * DK;
    const unsigned short* Kg = Kb + bh * SEQ * DK;
    const unsigned short* Vg = Vtg + bh * (size_t)DK * SEQ;

    // Q as B-operand: B[n=m=lane&31][k=lh*8+j]; frag t covers dk 16t..16t+15
    short8 qf[4];
#pragma unroll
    for (int t = 0; t < 4; ++t)
        qf[t] = *(const short8*)&Qg[(size_t)(w8 * 32 + l31) * DK + t * 16 + lh * 8];

    // staging geometry: thread -> (row = tid>>3, chunk = tid&7); global source is
    // pre-swizzled (chunk ^ row&7) so the linear gload_lds dest + swizzled ds_read
    // form the rule-21 involution pair.
    const int srow = tid >> 3;                // 0..63
    const int swz  = ((tid & 7) ^ (srow & 7)) * 8;
    const unsigned short* kgp = Kg + (size_t)srow * DK + swz;   // + kt*DK per tile
    const unsigned short* vgp = Vg + (size_t)srow * SEQ + swz;  // + kt per tile

    auto stage = [&](int bufsel, int kt) {
        unsigned short* Ks = (unsigned short*)(smem + bufsel * 16384);
        unsigned short* Vt = Ks + 8192 / 2;                      // 8192 B after K
        gload_lds16(kgp + (size_t)kt * DK, Ks + w8 * 512);       // wave base: 8 rows x 128B
        gload_lds16(vgp + kt,              Vt + w8 * 512);
    };

    floatx16 oacc[2];
    oacc[0] = (floatx16)(0.f);
    oacc[1] = (floatx16)(0.f);
    float lp = 0.f;                           // l partial for query m = w8*32 + l31

    // diag tile for this wave: its 32 q rows hit 64-key tile qt*256 + (w8>>1)*64,
    // in key-half dH = w8&1.
    const int diagkt = qt * QTILE + (w8 >> 1) * 64;
    const int dH     = w8 & 1;

    auto compute = [&](int bufsel, int kt) {
        const unsigned short* Ks = (const unsigned short*)(smem + bufsel * 16384);
        const unsigned short* Vt = Ks + 8192 / 2;

        // ---- S^T = K Q^T : sc0 keys 0..31, sc1 keys 32..63; col = q = lane&31 ----
        floatx16 sc0 = (floatx16)(0.f), sc1 = (floatx16)(0.f);
        __builtin_amdgcn_s_setprio(1);
#pragma unroll
        for (int t = 0; t < 4; ++t) {
            const int c  = 2 * t + lh;
            const int r0 = l31, r1 = 32 + l31;
            const short8 kf0 = *(const short8*)&Ks[r0 * 64 + ((c ^ (r0 & 7)) * 8)];
            const short8 kf1 = *(const short8*)&Ks[r1 * 64 + ((c ^ (r1 & 7)) * 8)];
            sc0 = __builtin_amdgcn_mfma_f32_32x32x16_bf16(kf0, qf[t], sc0, 0, 0, 0);
            sc1 = __builtin_amdgcn_mfma_f32_32x32x16_bf16(kf1, qf[t], sc1, 0, 0, 0);
        }
        __builtin_amdgcn_s_setprio(0);

        // ---- diagonal mask (wave-uniform tile + half) ----
        if (kt == diagkt) {
#pragma unroll
            for (int r = 0; r < 16; ++r) {
                const int key_loc = (r & 3) + 8 * (r >> 2) + 4 * lh;
                if (key_loc == l31) { if (dH) sc1[r] = -1e30f; else sc0[r] = -1e30f; }
            }
        }

        // ---- P = exp2(S^T): native v_exp_f32 + v_perm trunc pack; lp accumulates ----
        short8 pf[4];
        {
            union { unsigned int u[4]; short8 s8; } g0, g1, g2, g3;
#pragma unroll
            for (int d = 0; d < 4; ++d) {
                const float a0 = __builtin_amdgcn_exp2f(sc0[2 * d]);
                const float a1 = __builtin_amdgcn_exp2f(sc0[2 * d + 1]);
                g0.u[d] = __builtin_amdgcn_perm(fau(a1), fau(a0), 0x07060302u);
                const float b0 = __builtin_amdgcn_exp2f(sc0[8 + 2 * d]);
                const float b1 = __builtin_amdgcn_exp2f(sc0[8 + 2 * d + 1]);
                g1.u[d] = __builtin_amdgcn_perm(fau(b1), fau(b0), 0x07060302u);
                const float c0 = __builtin_amdgcn_exp2f(sc1[2 * d]);
                const float c1 = __builtin_amdgcn_exp2f(sc1[2 * d + 1]);
                g2.u[d] = __builtin_amdgcn_perm(fau(c1), fau(c0), 0x07060302u);
                const float d0 = __builtin_amdgcn_exp2f(sc1[8 + 2 * d]);
                const float d1 = __builtin_amdgcn_exp2f(sc1[8 + 2 * d + 1]);
                g3.u[d] = __builtin_amdgcn_perm(fau(d1), fau(d0), 0x07060302u);
                lp += ((a0 + a1) + (b0 + b1)) + ((c0 + c1) + (d0 + d1));
            }
            pf[0] = g0.s8; pf[1] = g1.s8; pf[2] = g2.s8; pf[3] = g3.s8;
        }

        // ---- O += P V  (sigma-permuted V: pf[ks] <-> V chunk 2ks+lh) ----
        __builtin_amdgcn_s_setprio(1);
#pragma unroll
        for (int nd = 0; nd < 2; ++nd)
#pragma unroll
            for (int ks = 0; ks < 4; ++ks) {
                const int r = nd * 32 + l31;
                const int c = 2 * ks + lh;
                const short8 vf = *(const short8*)&Vt[r * 64 + ((c ^ (r & 7)) * 8)];
                oacc[nd] = __builtin_amdgcn_mfma_f32_32x32x16_bf16(pf[ks], vf, oacc[nd], 0, 0, 0);
            }
        __builtin_amdgcn_s_setprio(0);
    };

    // prologue: stage tiles 0,1 into bufs 0,1 (4 loads in flight)
    stage(0, 0);
    stage(1, 64);

    int cur = 0;
    for (int j = 0; j < 32; ++j) {
        asm volatile("s_waitcnt vmcnt(2)" ::: "memory");   // retires tile j's K,V exactly
        __builtin_amdgcn_s_barrier();
        asm volatile("" ::: "memory");
        const int nxt = (j + 2 < 32) ? j + 2 : j - 30;     // wrap: dead restage of tiles 0/1
        const int nb  = (cur + 2 >= 3) ? cur - 1 : cur + 2;
        stage(nb, nxt * 64);
        compute(cur, j * 64);
        cur = (cur == 2) ? 0 : cur + 1;
    }

    // ---- epilogue: wave-local. l: lane-half combine; per-row l via shfl ----
    const float lptot = lp + __shfl_xor(lp, 32, 64);
    unsigned short* obase = attnb + ((size_t)b * SEQ + (size_t)qt * QTILE + w8 * 32) * D_MODEL
                          + h * DK;
    // 1.001953125 = 1/(1 - 2^-9): compensates mean truncation bias of bf16 P
    // (numerator uses trunc(P), denominator uses full-precision sums).
#pragma unroll
    for (int r = 0; r < 16; ++r) {
        const int mq = (r & 3) + 8 * (r >> 2) + 4 * lh;       // q row within wave's 32
        const float inv = 1.001953125f / __shfl(lptot, mq, 64); // lane mq holds l(q=mq)
        obase[(size_t)mq * D_MODEL + l31]      = f2bf(oacc[0][r] * inv);
        obase[(size_t)mq * D_MODEL + 32 + l31] = f2bf(oacc[1][r] * inv);
    }
}

extern "C" void kernel_launch(void* const* d_in, const int* in_sizes, int n_in,
                              void* d_out, int out_size, void* d_ws, size_t ws_size,
                              hipStream_t stream) {
    const float* x     = (const float*)d_in[0];
    const float* w_qkv = (const float*)d_in[1];
    const float* w_out = (const float*)d_in[2];
    const float* b_out = (const float*)d_in[3];
    float* out = (float*)d_out;

    const int M = BATCH * SEQ;                                   // 4096
    const size_t X_ELEMS    = (size_t)M * D_MODEL;
    const size_t WQKV_ELEMS = (size_t)3 * D_MODEL * D_MODEL;
    const size_t WOUT_ELEMS = (size_t)D_MODEL * D_MODEL;
    const size_t QKV_ELEMS  = (size_t)M * 3 * D_MODEL;
    const size_t HEAD_ELEMS = (size_t)BATCH * NHEADS * SEQ * DK;

    unsigned short* xb    = (unsigned short*)d_ws;
    unsigned short* wqkvb = xb + X_ELEMS;
    unsigned short* woutb = wqkvb + WQKV_ELEMS;
    unsigned short* qkvb  = woutb + WOUT_ELEMS;
    unsigned short* Qb    = qkvb + QKV_ELEMS;
    unsigned short* Kb    = Qb + HEAD_ELEMS;
    unsigned short* Vtg   = Kb + HEAD_ELEMS;                     // [B,H,64,S] sigma-permuted
    unsigned short* attnb = Vtg + HEAD_ELEMS;

    // 0) pack all inputs to bf16
    pack_all<<<(X8 + W8 + O8 + 255) / 256, 256, 0, stream>>>(x, w_qkv, w_out, xb, wqkvb, woutb);

    // 1) qkvb = xb @ wqkvb^T  (256^2 8-phase pipeline, (kk,mh) phases)
    gemm_qkv_8ph<<<(QKV_M / 256) * (QKV_N / 256), 512, 0, stream>>>(xb, wqkvb, qkvb);

    // 2) RoPE pack + sigma-permuted V transpose
    {
        dim3 grid(SEQ / 64, NHEADS, BATCH);
        rope_vtrans<<<grid, 256, 0, stream>>>(qkvb, Qb, Kb, Vtg);
    }
    // 3) flash attention (QTILE=256, async-staged triple-buffer counted-vmcnt)
    {
        dim3 grid(SEQ / QTILE, NHEADS, BATCH);
        flash_attn<<<grid, 512, 0, stream>>>(Qb, Kb, Vtg, attnb);
    }
    // 4) out = attnb @ woutb^T + b_out  (128^2 8-phase pipeline, 256 blocks)
    gemm_out_8ph<<<(OUT_M / 128) * (OUT_N / 128), 512, 0, stream>>>(attnb, woutb, b_out, out);
}

// Round 9
// 184.584 us; speedup vs baseline: 1.0160x; 1.0160x over previous
//
#include <hip/hip_runtime.h>
#include <hip/hip_bf16.h>
#include <math.h>
#include <type_traits>

#define D_MODEL 1024
#define NHEADS  16
#define DK      64
#define SEQ     2048
#define BATCH   2
#define QTILE   128

typedef __attribute__((ext_vector_type(8)))  short  short8;
typedef __attribute__((ext_vector_type(8)))  unsigned short ushort8;
typedef __attribute__((ext_vector_type(4)))  float  floatx4;
typedef __attribute__((ext_vector_type(16))) float  floatx16;

template <int N> using IC = std::integral_constant<int, N>;

__device__ __forceinline__ unsigned short f2bf(float f) {      // RNE
    union { float f; unsigned int u; } v; v.f = f;
    unsigned int u = v.u;
    return (unsigned short)((u + 0x7FFFu + ((u >> 16) & 1u)) >> 16);
}
__device__ __forceinline__ float bf2f(unsigned short u) {
    union { unsigned int u; float f; } v; v.u = ((unsigned int)u) << 16;
    return v.f;
}
__device__ __forceinline__ unsigned int fau(float f) {
    union { float f; unsigned int u; } v; v.f = f; return v.u;
}

// async global->LDS, 16B per lane. LDS dest = wave-uniform base + lane*16.
__device__ __forceinline__ void gload_lds16(const unsigned short* g, unsigned short* l) {
    __builtin_amdgcn_global_load_lds((__attribute__((address_space(1))) const void*)g,
                                     (__attribute__((address_space(3))) void*)l,
                                     16, 0, 0);
}

// ---------------- fused fp32 -> bf16 pack of x, w_qkv, w_out ----------------
#define X8 ((BATCH * SEQ * D_MODEL) / 8)
#define W8 ((3 * D_MODEL * D_MODEL) / 8)
#define O8 ((D_MODEL * D_MODEL) / 8)
__global__ __launch_bounds__(256) void pack_all(const float* __restrict__ x,
                                                const float* __restrict__ wq,
                                                const float* __restrict__ wo,
                                                unsigned short* __restrict__ xb,
                                                unsigned short* __restrict__ wqb,
                                                unsigned short* __restrict__ wob) {
    const int t = blockIdx.x * blockDim.x + threadIdx.x;
    const float* src; unsigned short* dst; int idx;
    if (t < X8)           { src = x;  dst = xb;  idx = t; }
    else if (t < X8 + W8) { src = wq; dst = wqb; idx = t - X8; }
    else if (t < X8 + W8 + O8) { src = wo; dst = wob; idx = t - X8 - W8; }
    else return;
    const float4 a = ((const float4*)src)[2 * idx];
    const float4 b = ((const float4*)src)[2 * idx + 1];
    short8 o;
    o[0] = (short)f2bf(a.x); o[1] = (short)f2bf(a.y);
    o[2] = (short)f2bf(a.z); o[3] = (short)f2bf(a.w);
    o[4] = (short)f2bf(b.x); o[5] = (short)f2bf(b.y);
    o[6] = (short)f2bf(b.z); o[7] = (short)f2bf(b.w);
    ((short8*)dst)[idx] = o;
}

// ---------------- QKV GEMM: 256x256 tile, BK=64, 8-phase counted-vmcnt pipeline ----
// Phase factorization (kk, mh): 8 ds_read_b128 + 16 MFMA per phase, 32 reads/K-tile.
// Staging order per tile: B0,B1,A0,A1 (2 gload each). Waits traced:
//   P0 vmcnt(2) drains B0,B1,A0(t); P1 vmcnt(2) drains A1(t); P2 vmcnt(4) no-op;
//   P3 vmcnt(4) drains B0(t+1) (3 phases old). Never drains to 0.
// T2 swizzle both-sides; T5 setprio; T1 XCD-contiguous block swizzle.
#define QKV_M 4096
#define QKV_N 3072
#define QKV_K 1024
#define QKV_NT (QKV_K / 64)

__global__ __launch_bounds__(512, 2) void gemm_qkv_8ph(const unsigned short* __restrict__ A,
                                                        const unsigned short* __restrict__ B,
                                                        unsigned short* __restrict__ C) {
    __shared__ __align__(16) unsigned short As[2][256][64];   // 64 KB
    __shared__ __align__(16) unsigned short Bs[2][256][64];   // 64 KB

    const int tid  = threadIdx.x;
    const int w    = tid >> 6;        // wave 0..7
    const int lane = tid & 63;
    const int quad = lane >> 4;
    const int lcol = lane & 15;
    const int wr   = w >> 2;          // 0..1  (M half: 128 rows)
    const int wc   = w & 3;           // 0..3  (N quarter: 64 cols)

    // XCD-contiguous swizzle: 192 blocks = 8 XCDs x 24
    const int f  = blockIdx.x;
    const int wg = (f & 7) * 24 + (f >> 3);
    const int tn = (wg % (QKV_N / 256)) * 256;
    const int tm = (wg / (QKV_N / 256)) * 256;

    const int srow8 = lane >> 3;      // staging: row within 8-row block
    const int sj    = lane & 7;       // staging: 16B chunk within row

    // stage A-group mh (rows {mh*64..+64} u {128+mh*64..+64}) of K-tile kt into buf
    auto stageA = [&](int buf, int kt, int mh) {
#pragma unroll
        for (int c = 0; c < 2; ++c) {
            const int r0 = mh * 64 + c * 128 + w * 8;
            const int r  = r0 + srow8;
            gload_lds16(A + (size_t)(tm + r) * QKV_K + kt * 64 + ((sj ^ (r & 7)) * 8),
                        &As[buf][r0][0]);
        }
    };
    // stage B-group nh (rows {k*64 + nh*32 .. +32 : k=0..3}) of K-tile kt into buf
    auto stageB = [&](int buf, int kt, int nh) {
#pragma unroll
        for (int c = 0; c < 2; ++c) {
            const int rho0 = c * 64 + w * 8;
            const int r0   = (rho0 >> 5) * 64 + nh * 32 + (rho0 & 31);
            const int r    = r0 + srow8;
            gload_lds16(B + (size_t)(tn + r) * QKV_K + kt * 64 + ((sj ^ (r & 7)) * 8),
                        &Bs[buf][r0][0]);
        }
    };

    floatx4 acc[8][4];
#pragma unroll
    for (int i = 0; i < 8; ++i)
#pragma unroll
        for (int j = 0; j < 4; ++j) acc[i][j] = (floatx4){0.f, 0.f, 0.f, 0.f};

    // phase (kk, mh): A-half x all-B at k-slice kk; 8 ds_read_b128 + 16 MFMA
    auto do_phase = [&](int buf, auto vmc, auto kkc, auto mhc, auto stager) {
        constexpr int VM = decltype(vmc)::value;
        constexpr int kk = decltype(kkc)::value;
        constexpr int mh = decltype(mhc)::value;
        if constexpr (VM == 2) asm volatile("s_waitcnt vmcnt(2)" ::: "memory");
        else                   asm volatile("s_waitcnt vmcnt(4)" ::: "memory");
        __builtin_amdgcn_s_barrier();
        asm volatile("" ::: "memory");          // no LDS reads above the barrier
        short8 a[4], b[4];
#pragma unroll
        for (int i = 0; i < 4; ++i) {
            const int r = wr * 128 + mh * 64 + i * 16 + lcol;
            a[i] = *(const short8*)&As[buf][r][((kk * 4 + quad) ^ (r & 7)) * 8];
        }
#pragma unroll
        for (int j = 0; j < 4; ++j) {
            const int r = wc * 64 + j * 16 + lcol;
            b[j] = *(const short8*)&Bs[buf][r][((kk * 4 + quad) ^ (r & 7)) * 8];
        }
        stager();
        __builtin_amdgcn_s_setprio(1);
#pragma unroll
        for (int i = 0; i < 4; ++i)
#pragma unroll
            for (int j = 0; j < 4; ++j)
                acc[mh * 4 + i][j] = __builtin_amdgcn_mfma_f32_16x16x32_bf16(
                    a[i], b[j], acc[mh * 4 + i][j], 0, 0, 0);
        __builtin_amdgcn_s_setprio(0);
    };

    // prologue: tile 0 -> buf 0, staging order B0 B1 A0 A1
    stageB(0, 0, 0); stageB(0, 0, 1); stageA(0, 0, 0); stageA(0, 0, 1);

    for (int t = 0; t < QKV_NT; ++t) {
        const int buf = t & 1, nb = buf ^ 1;
        const int kn = (t + 1 == QKV_NT) ? 0 : t + 1;   // wrap: dead restage keeps invariant
        do_phase(buf, IC<2>{}, IC<0>{}, IC<0>{}, [&] { stageB(nb, kn, 0); });
        do_phase(buf, IC<2>{}, IC<0>{}, IC<1>{}, [&] { stageB(nb, kn, 1); });
        do_phase(buf, IC<4>{}, IC<1>{}, IC<0>{}, [&] { stageA(nb, kn, 0); });
        do_phase(buf, IC<4>{}, IC<1>{}, IC<1>{}, [&] { stageA(nb, kn, 1); });
    }

    // epilogue: C-write (bf16)
#pragma unroll
    for (int i = 0; i < 8; ++i) {
#pragma unroll
        for (int rr = 0; rr < 4; ++rr) {
            const int row = tm + wr * 128 + i * 16 + quad * 4 + rr;
#pragma unroll
            for (int jf = 0; jf < 4; ++jf) {
                const int col = tn + wc * 64 + jf * 16 + lcol;
                C[(size_t)row * QKV_N + col] = f2bf(acc[i][jf][rr]);
            }
        }
    }
}

// ---------------- out-proj GEMM: 128x128 tile, BK=64, 8-phase counted-vmcnt ----------
#define OUT_M 4096
#define OUT_N 1024
#define OUT_K 1024
#define OUT_NT (OUT_K / 64)

__global__ __launch_bounds__(512, 2) void gemm_out_8ph(const unsigned short* __restrict__ A,
                                                       const unsigned short* __restrict__ B,
                                                       const float* __restrict__ bias,
                                                       float* __restrict__ C) {
    __shared__ __align__(16) unsigned short As[2][128][64];   // 32 KB
    __shared__ __align__(16) unsigned short Bs[2][128][64];   // 32 KB

    const int tid  = threadIdx.x;
    const int w    = tid >> 6;        // wave 0..7
    const int lane = tid & 63;
    const int quad = lane >> 4;
    const int lcol = lane & 15;
    const int wr   = w >> 2;          // 0..1  (M half: 64 rows)
    const int wc   = w & 3;           // 0..3  (N quarter: 32 cols)

    // XCD-contiguous swizzle: 256 blocks = 8 XCDs x 32
    const int f  = blockIdx.x;
    const int wg = (f & 7) * 32 + (f >> 3);
    const int tn = (wg & 7) * 128;    // OUT_N/128 = 8
    const int tm = (wg >> 3) * 128;   // OUT_M/128 = 32

    const int srow8 = lane >> 3;
    const int sj    = lane & 7;

    // A-group mh: rows {mh*32+[0,32)} u {64+mh*32+[0,32)}; 8 waves x 8 rows, 1 gload
    auto stageA = [&](int buf, int kt, int mh) {
        const int r0 = (w & 3) * 8 + mh * 32 + (w >> 2) * 64;
        const int r  = r0 + srow8;
        gload_lds16(A + (size_t)(tm + r) * OUT_K + kt * 64 + ((sj ^ (r & 7)) * 8),
                    &As[buf][r0][0]);
    };
    // B-group nh: rows {c*32 + nh*16 + [0,16) : c=0..3}; 8 waves x 8 rows, 1 gload
    auto stageB = [&](int buf, int kt, int nh) {
        const int r0 = (w >> 1) * 32 + nh * 16 + (w & 1) * 8;
        const int r  = r0 + srow8;
        gload_lds16(B + (size_t)(tn + r) * OUT_K + kt * 64 + ((sj ^ (r & 7)) * 8),
                    &Bs[buf][r0][0]);
    };

    floatx4 acc[4][2];
#pragma unroll
    for (int i = 0; i < 4; ++i)
#pragma unroll
        for (int j = 0; j < 2; ++j) acc[i][j] = (floatx4){0.f, 0.f, 0.f, 0.f};

    auto do_phase = [&](int buf, auto vmc, auto kkc, auto mhc, auto stager) {
        constexpr int VM = decltype(vmc)::value;
        constexpr int kk = decltype(kkc)::value;
        constexpr int mh = decltype(mhc)::value;
        if constexpr (VM == 1) asm volatile("s_waitcnt vmcnt(1)" ::: "memory");
        else                   asm volatile("s_waitcnt vmcnt(2)" ::: "memory");
        __builtin_amdgcn_s_barrier();
        asm volatile("" ::: "memory");          // no LDS reads above the barrier
        short8 a[2], b[2];
#pragma unroll
        for (int i = 0; i < 2; ++i) {
            const int r = wr * 64 + mh * 32 + i * 16 + lcol;
            a[i] = *(const short8*)&As[buf][r][((kk * 4 + quad) ^ (r & 7)) * 8];
        }
#pragma unroll
        for (int j = 0; j < 2; ++j) {
            const int r = wc * 32 + j * 16 + lcol;
            b[j] = *(const short8*)&Bs[buf][r][((kk * 4 + quad) ^ (r & 7)) * 8];
        }
        stager();
        __builtin_amdgcn_s_setprio(1);
#pragma unroll
        for (int i = 0; i < 2; ++i)
#pragma unroll
            for (int j = 0; j < 2; ++j)
                acc[mh * 2 + i][j] = __builtin_amdgcn_mfma_f32_16x16x32_bf16(
                    a[i], b[j], acc[mh * 2 + i][j], 0, 0, 0);
        __builtin_amdgcn_s_setprio(0);
    };

    // prologue: tile 0 -> buf 0, order B0 B1 A0 A1
    stageB(0, 0, 0); stageB(0, 0, 1); stageA(0, 0, 0); stageA(0, 0, 1);

    for (int t = 0; t < OUT_NT; ++t) {
        const int buf = t & 1, nb = buf ^ 1;
        const int kn = (t + 1 == OUT_NT) ? 0 : t + 1;   // wrap: dead restage keeps invariant
        do_phase(buf, IC<1>{}, IC<0>{}, IC<0>{}, [&] { stageB(nb, kn, 0); });
        do_phase(buf, IC<1>{}, IC<0>{}, IC<1>{}, [&] { stageB(nb, kn, 1); });
        do_phase(buf, IC<2>{}, IC<1>{}, IC<0>{}, [&] { stageA(nb, kn, 0); });
        do_phase(buf, IC<2>{}, IC<1>{}, IC<1>{}, [&] { stageA(nb, kn, 1); });
    }

    // epilogue: fp32 C-write + bias
#pragma unroll
    for (int i = 0; i < 4; ++i) {
#pragma unroll
        for (int rr = 0; rr < 4; ++rr) {
            const int row = tm + wr * 64 + i * 16 + quad * 4 + rr;
#pragma unroll
            for (int j = 0; j < 2; ++j) {
                const int col = tn + wc * 32 + j * 16 + lcol;
                C[(size_t)row * OUT_N + col] = acc[i][j][rr] + bias[col];
            }
        }
    }
}

// ---------------- fused RoPE pack (Q*0.125*log2e, K) + sigma-permuted V transpose ---
// Key u within each 64-tile is stored at column c(u) = (u&48) | (8*((u>>2)&1) + (u&3)
// + 4*((u>>3)&1)) so PV's A-operand (= S^T C-regs) and B-operand (V) agree on the
// 32x32x16 MFMA k-index mapping. RoPE q/k pair loads vectorized to single u32 (G13).
__global__ __launch_bounds__(256) void rope_vtrans(const unsigned short* __restrict__ qkvb,
                                                   unsigned short* __restrict__ Qb,
                                                   unsigned short* __restrict__ Kb,
                                                   unsigned short* __restrict__ Vtg) {
    const int st = blockIdx.x, h = blockIdx.y, b = blockIdx.z;
    const int tid = threadIdx.x;
    const int s0 = st * 64;

    // ---- RoPE on Q,K ----
    const int i  = tid & 31;
    const int r0 = tid >> 5;                   // 0..7
    const float inv_freq = exp2f(-(2.0f * (float)i / (float)DK) * log2f(50.0f));
    const float QSCALE = 0.125f * 1.44269504f; // 1/sqrt(dk) * log2(e)
#pragma unroll
    for (int pass = 0; pass < 8; ++pass) {
        const int s = s0 + r0 + pass * 8;
        const size_t in_base = ((size_t)(b * SEQ + s)) * (3 * D_MODEL) + h * DK + 2 * i;
        const unsigned int qin = *(const unsigned int*)&qkvb[in_base];
        const unsigned int kin = *(const unsigned int*)&qkvb[in_base + D_MODEL];
        const float q0 = bf2f((unsigned short)(qin & 0xFFFFu));
        const float q1 = bf2f((unsigned short)(qin >> 16));
        const float k0 = bf2f((unsigned short)(kin & 0xFFFFu));
        const float k1 = bf2f((unsigned short)(kin >> 16));
        float sn, cs;
        __sincosf((float)s * inv_freq, &sn, &cs);
        const size_t ob = (((size_t)(b * NHEADS + h)) * SEQ + s) * DK + 2 * i;
        const unsigned int qw = (unsigned int)f2bf((q0 * cs - q1 * sn) * QSCALE)
                              | ((unsigned int)f2bf((q1 * cs + q0 * sn) * QSCALE) << 16);
        const unsigned int kw = (unsigned int)f2bf(k0 * cs - k1 * sn)
                              | ((unsigned int)f2bf(k1 * cs + k0 * sn) << 16);
        *(unsigned int*)&Qb[ob] = qw;
        *(unsigned int*)&Kb[ob] = kw;
    }

    // ---- V transpose with sigma column permutation ----
    __shared__ unsigned short Lt[64][65];
    const int r = tid >> 3;                    // 0..31 (key within tile)
    const int c = (tid & 7) * 8;
    const size_t in_row = ((size_t)(b * SEQ + s0 + r)) * (3 * D_MODEL) + 2 * D_MODEL + h * DK + c;
    const ushort8 v0 = *(const ushort8*)&qkvb[in_row];
    const ushort8 v1 = *(const ushort8*)&qkvb[in_row + (size_t)32 * (3 * D_MODEL)];
    const int u0 = r, u1 = r + 32;
    const int kc0 = (u0 & 48) | (8 * ((u0 >> 2) & 1) + (u0 & 3) + 4 * ((u0 >> 3) & 1));
    const int kc1 = (u1 & 48) | (8 * ((u1 >> 2) & 1) + (u1 & 3) + 4 * ((u1 >> 3) & 1));
#pragma unroll
    for (int j = 0; j < 8; ++j) Lt[c + j][kc0] = v0[j];
#pragma unroll
    for (int j = 0; j < 8; ++j) Lt[c + j][kc1] = v1[j];
    __syncthreads();
    const size_t bh = (size_t)(b * NHEADS + h);
    ushort8 o0, o1;
#pragma unroll
    for (int j = 0; j < 8; ++j) { o0[j] = Lt[r][c + j]; o1[j] = Lt[r + 32][c + j]; }
    unsigned short* orow = Vtg + (bh * DK + r) * SEQ + s0 + c;   // r = d-row
    *(ushort8*)orow = o0;
    *(ushort8*)(orow + (size_t)32 * SEQ) = o1;
}

// ---------------- flash attention: QTILE=128, 8 waves, double-buffered K/V LDS ----
// Measured-best flash form (r3: 43.96us). One barrier per 64-key tile: {write buf;
// barrier; issue next loads; compute}. Three structural alternatives (deferred-PV
// 3-buf, 64qx32k LDS-reuse, async gload_lds counted-vmcnt) all measured WORSE
// (47.4/47.8/50.5) — do not re-attempt piecemeal grafts on this structure.
#define LDW 72

__global__ __launch_bounds__(512, 4) void flash_attn(const unsigned short* __restrict__ Qb,
                                                     const unsigned short* __restrict__ Kb,
                                                     const unsigned short* __restrict__ Vtg,
                                                     unsigned short* __restrict__ attnb) {
    const int tid  = threadIdx.x;
    const int wave = tid >> 6;
    const int lane = tid & 63;
    const int l31  = lane & 31;
    const int lh   = lane >> 5;               // lane half (k-group)
    const int mh2  = wave & 3;                // m-quarter (32 q rows of 128)
    const int kh   = wave >> 2;               // key-half (32 keys of 64)
    const int kb   = kh * 32;

    // XCD-grouping swizzle: 512 blocks, assume round-robin f%8 -> XCD
    const int f  = blockIdx.x + gridDim.x * (blockIdx.y + gridDim.y * blockIdx.z);
    const int w  = (f & 7) * 64 + (f >> 3);   // bijective (512 % 8 == 0)
    const int qt = w & 15;                    // 0..15 (tiles of 128 queries)
    const int h  = (w >> 4) & 15;
    const int b  = w >> 8;

    __shared__ __align__(16) unsigned char smem[36864];          // 2 x (Ks 9216 + Vt 9216)
    unsigned short (*Ks0)[LDW] = (unsigned short (*)[LDW])(smem);
    unsigned short (*Vt0)[LDW] = (unsigned short (*)[LDW])(smem +  9216);
    unsigned short (*Ks1)[LDW] = (unsigned short (*)[LDW])(smem + 18432);
    unsigned short (*Vt1)[LDW] = (unsigned short (*)[LDW])(smem + 27648);
    // epilogue overlays (staging dead): 128*68*4 + 2*128*4 = 35840 <= 36864
    float (*Ored)[68] = (float (*)[68])smem;
    float* lred0 = (float*)(smem + 34816);
    float* lred1 = lred0 + 128;

    const size_t bh = (size_t)(b * NHEADS + h);
    const unsigned short* Qg = Qb + (bh * SEQ + (size_t)qt * QTILE) * DK;
    const unsigned short* Kg = Kb + bh * SEQ * DK;
    const unsigned short* Vg = Vtg + bh * (size_t)DK * SEQ;

    // Q as B-operand: B[n=m=lane&31][k=lh*8+j]; frag t covers dk 16t..16t+15
    short8 qf[4];
#pragma unroll
    for (int t = 0; t < 4; ++t)
        qf[t] = *(const short8*)&Qg[(size_t)(mh2 * 32 + l31) * DK + t * 16 + lh * 8];

    // staging: 512 threads, each 1 short8 into Ks and 1 into Vt (64 rows x 64 cols)
    const int strow = tid >> 3;               // 0..63
    const int stcol = (tid & 7) * 8;
    const unsigned short* kg = &Kg[(size_t)strow * DK + stcol];
    const unsigned short* vg = &Vg[(size_t)strow * SEQ + stcol];

    short8 kr = *(const short8*)&kg[0];
    short8 vr = *(const short8*)&vg[0];

    floatx16 oacc[2];
    oacc[0] = (floatx16)(0.f);
    oacc[1] = (floatx16)(0.f);
    float lp = 0.f;                           // scalar l partial: query m = mh2*32+l31

    // diagonal tile for this wave: key global == q global  <=>  kt + kb == qt*128 + mh2*32
    const int diagkt = qt * QTILE + mh2 * 32 - kb;

    auto compute = [&](unsigned short (*Ks)[LDW], unsigned short (*Vt)[LDW], int kt) {
        // ---- S^T = K Q^T : C[row=key scatter][col=m=lane&31], 4 MFMAs ----
        floatx16 sc = (floatx16)(0.f);
        __builtin_amdgcn_s_setprio(1);
#pragma unroll
        for (int t = 0; t < 4; ++t) {
            const short8 kf = *(short8*)&Ks[kb + l31][t * 16 + lh * 8];
            sc = __builtin_amdgcn_mfma_f32_32x32x16_bf16(kf, qf[t], sc, 0, 0, 0);
        }
        __builtin_amdgcn_s_setprio(0);

        // ---- diagonal mask ----
        if (kt == diagkt) {
#pragma unroll
            for (int r = 0; r < 16; ++r) {
                const int key_loc = (r & 3) + 8 * (r >> 2) + 4 * lh;
                if (key_loc == l31) sc[r] = -1e30f;
            }
        }

        // ---- P = exp2(S^T): native v_exp_f32 + v_perm trunc pack; lp accumulates ----
        short8 pf0, pf1;
        {
            union { unsigned int u[4]; short8 s8; } a, c;
#pragma unroll
            for (int d = 0; d < 4; ++d) {
                const float e0 = __builtin_amdgcn_exp2f(sc[2 * d]);
                const float e1 = __builtin_amdgcn_exp2f(sc[2 * d + 1]);
                a.u[d] = __builtin_amdgcn_perm(fau(e1), fau(e0), 0x07060302u);
                const float f0 = __builtin_amdgcn_exp2f(sc[8 + 2 * d]);
                const float f1 = __builtin_amdgcn_exp2f(sc[8 + 2 * d + 1]);
                c.u[d] = __builtin_amdgcn_perm(fau(f1), fau(f0), 0x07060302u);
                lp += (e0 + e1) + (f0 + f1);
            }
            pf0 = a.s8;
            pf1 = c.s8;
        }

        // ---- O += P V  (V pre-permuted so k-indices align) ----
        __builtin_amdgcn_s_setprio(1);
#pragma unroll
        for (int nd = 0; nd < 2; ++nd) {
            const short8 vfa = *(short8*)&Vt[nd * 32 + l31][kb + lh * 8];        // keys 0..15
            const short8 vfb = *(short8*)&Vt[nd * 32 + l31][kb + 16 + lh * 8];   // keys 16..31
            oacc[nd] = __builtin_amdgcn_mfma_f32_32x32x16_bf16(pf0, vfa, oacc[nd], 0, 0, 0);
            oacc[nd] = __builtin_amdgcn_mfma_f32_32x32x16_bf16(pf1, vfb, oacc[nd], 0, 0, 0);
        }
        __builtin_amdgcn_s_setprio(0);
    };

    for (int kt = 0; kt < SEQ; kt += 128) {
        // ---- phase A: buffer 0, keys [kt, kt+64) ----
        *(short8*)&Ks0[strow][stcol] = kr;
        *(short8*)&Vt0[strow][stcol] = vr;
        __syncthreads();
        kr = *(const short8*)&kg[(size_t)(kt + 64) * DK];
        vr = *(const short8*)&vg[kt + 64];
        compute(Ks0, Vt0, kt);

        // ---- phase B: buffer 1, keys [kt+64, kt+128) ----
        *(short8*)&Ks1[strow][stcol] = kr;
        *(short8*)&Vt1[strow][stcol] = vr;
        __syncthreads();
        const int ktn = (kt + 128 < SEQ) ? kt + 128 : 0;
        kr = *(const short8*)&kg[(size_t)ktn * DK];
        vr = *(const short8*)&vg[ktn];
        compute(Ks1, Vt1, kt + 64);
    }

    // ---- l: combine the two lane-halves (same m, disjoint keys) ----
    const float lptot = lp + __shfl_xor(lp, 32, 64);

    // ---- cross-wave (key-half) reduction through LDS overlay ----
    __syncthreads();                          // staging buffers dead
    if (lh == 0) {
        if (kh == 0) lred0[mh2 * 32 + l31] = lptot;
        else         lred1[mh2 * 32 + l31] = lptot;
    }
    if (kh == 1) {
#pragma unroll
        for (int r = 0; r < 16; ++r) {
            const int m = mh2 * 32 + (r & 3) + 8 * (r >> 2) + 4 * lh;
            Ored[m][l31]      = oacc[0][r];
            Ored[m][32 + l31] = oacc[1][r];
        }
    }
    __syncthreads();
    if (kh == 0) {
        unsigned short* obase = attnb + ((size_t)b * SEQ + (size_t)qt * QTILE) * D_MODEL + h * DK;
        // 1.001953125 = 1/(1 - 2^-9): compensates mean truncation bias of bf16 P
        // (numerator uses trunc(P), denominator uses full-precision sums).
#pragma unroll
        for (int r = 0; r < 16; ++r) {
            const int m = mh2 * 32 + (r & 3) + 8 * (r >> 2) + 4 * lh;
            const float inv = 1.001953125f / (lred0[m] + lred1[m]);
            const float v0 = (oacc[0][r] + Ored[m][l31]) * inv;
            const float v1 = (oacc[1][r] + Ored[m][32 + l31]) * inv;
            obase[(size_t)m * D_MODEL + l31]      = f2bf(v0);
            obase[(size_t)m * D_MODEL + 32 + l31] = f2bf(v1);
        }
    }
}

extern "C" void kernel_launch(void* const* d_in, const int* in_sizes, int n_in,
                              void* d_out, int out_size, void* d_ws, size_t ws_size,
                              hipStream_t stream) {
    const float* x     = (const float*)d_in[0];
    const float* w_qkv = (const float*)d_in[1];
    const float* w_out = (const float*)d_in[2];
    const float* b_out = (const float*)d_in[3];
    float* out = (float*)d_out;

    const int M = BATCH * SEQ;                                   // 4096
    const size_t X_ELEMS    = (size_t)M * D_MODEL;
    const size_t WQKV_ELEMS = (size_t)3 * D_MODEL * D_MODEL;
    const size_t WOUT_ELEMS = (size_t)D_MODEL * D_MODEL;
    const size_t QKV_ELEMS  = (size_t)M * 3 * D_MODEL;
    const size_t HEAD_ELEMS = (size_t)BATCH * NHEADS * SEQ * DK;

    unsigned short* xb    = (unsigned short*)d_ws;
    unsigned short* wqkvb = xb + X_ELEMS;
    unsigned short* woutb = wqkvb + WQKV_ELEMS;
    unsigned short* qkvb  = woutb + WOUT_ELEMS;
    unsigned short* Qb    = qkvb + QKV_ELEMS;
    unsigned short* Kb    = Qb + HEAD_ELEMS;
    unsigned short* Vtg   = Kb + HEAD_ELEMS;                     // [B,H,64,S] sigma-permuted
    unsigned short* attnb = Vtg + HEAD_ELEMS;

    // 0) pack all inputs to bf16
    pack_all<<<(X8 + W8 + O8 + 255) / 256, 256, 0, stream>>>(x, w_qkv, w_out, xb, wqkvb, woutb);

    // 1) qkvb = xb @ wqkvb^T  (256^2 8-phase pipeline, (kk,mh) phases)
    gemm_qkv_8ph<<<(QKV_M / 256) * (QKV_N / 256), 512, 0, stream>>>(xb, wqkvb, qkvb);

    // 2) RoPE pack + sigma-permuted V transpose
    {
        dim3 grid(SEQ / 64, NHEADS, BATCH);
        rope_vtrans<<<grid, 256, 0, stream>>>(qkvb, Qb, Kb, Vtg);
    }
    // 3) flash attention (QTILE=128, 8 waves, dbuf K/V — measured-best r3 form)
    {
        dim3 grid(SEQ / QTILE, NHEADS, BATCH);
        flash_attn<<<grid, 512, 0, stream>>>(Qb, Kb, Vtg, attnb);
    }
    // 4) out = attnb @ woutb^T + b_out  (128^2 8-phase pipeline, 256 blocks)
    gemm_out_8ph<<<(OUT_M / 128) * (OUT_N / 128), 512, 0, stream>>>(attnb, woutb, b_out, out);
}

// Round 10
// 174.798 us; speedup vs baseline: 1.0729x; 1.0560x over previous
//
#include <hip/hip_runtime.h>
#include <hip/hip_bf16.h>
#include <math.h>
#include <type_traits>

#define D_MODEL 1024
#define NHEADS  16
#define DK      64
#define SEQ     2048
#define BATCH   2
#define QTILE   128

typedef __attribute__((ext_vector_type(8)))  short  short8;
typedef __attribute__((ext_vector_type(8)))  unsigned short ushort8;
typedef __attribute__((ext_vector_type(4)))  float  floatx4;
typedef __attribute__((ext_vector_type(16))) float  floatx16;

template <int N> using IC = std::integral_constant<int, N>;

__device__ __forceinline__ unsigned short f2bf(float f) {      // RNE
    union { float f; unsigned int u; } v; v.f = f;
    unsigned int u = v.u;
    return (unsigned short)((u + 0x7FFFu + ((u >> 16) & 1u)) >> 16);
}
__device__ __forceinline__ float bf2f(unsigned short u) {
    union { unsigned int u; float f; } v; v.u = ((unsigned int)u) << 16;
    return v.f;
}
__device__ __forceinline__ unsigned int fau(float f) {
    union { float f; unsigned int u; } v; v.f = f; return v.u;
}

// async global->LDS, 16B per lane. LDS dest = wave-uniform base + lane*16.
__device__ __forceinline__ void gload_lds16(const unsigned short* g, unsigned short* l) {
    __builtin_amdgcn_global_load_lds((__attribute__((address_space(1))) const void*)g,
                                     (__attribute__((address_space(3))) void*)l,
                                     16, 0, 0);
}

// ---------------- fused fp32 -> bf16 pack of x, w_qkv, w_out ----------------
#define X8 ((BATCH * SEQ * D_MODEL) / 8)
#define W8 ((3 * D_MODEL * D_MODEL) / 8)
#define O8 ((D_MODEL * D_MODEL) / 8)
__global__ __launch_bounds__(256) void pack_all(const float* __restrict__ x,
                                                const float* __restrict__ wq,
                                                const float* __restrict__ wo,
                                                unsigned short* __restrict__ xb,
                                                unsigned short* __restrict__ wqb,
                                                unsigned short* __restrict__ wob) {
    const int t = blockIdx.x * blockDim.x + threadIdx.x;
    const float* src; unsigned short* dst; int idx;
    if (t < X8)           { src = x;  dst = xb;  idx = t; }
    else if (t < X8 + W8) { src = wq; dst = wqb; idx = t - X8; }
    else if (t < X8 + W8 + O8) { src = wo; dst = wob; idx = t - X8 - W8; }
    else return;
    const float4 a = ((const float4*)src)[2 * idx];
    const float4 b = ((const float4*)src)[2 * idx + 1];
    short8 o;
    o[0] = (short)f2bf(a.x); o[1] = (short)f2bf(a.y);
    o[2] = (short)f2bf(a.z); o[3] = (short)f2bf(a.w);
    o[4] = (short)f2bf(b.x); o[5] = (short)f2bf(b.y);
    o[6] = (short)f2bf(b.z); o[7] = (short)f2bf(b.w);
    ((short8*)dst)[idx] = o;
}

// ---------------- QKV GEMM: 256x192 tile, BK=64, 8-phase counted-vmcnt pipeline ----
// BN=192 -> grid 16x16 = 256 blocks = exactly 1/CU (BN=256 gave 192 blocks: 25% of
// CUs idle). Per wave: 128 rows x 48 cols (3 frags), acc[8][3]; phase (kk,mh) =
// 7 ds_read_b128 + 12 MFMA. Staging groups per tile: g0=B rows 0-127 (2 gloads),
// g1=B 128-191 (1), g2=A mh0 (2), g3=A mh1 (2); issued at P0..P3. Waits traced:
//   P0 vmcnt(2): drains g0,g1,g2(t), leaves g3   P1 vmcnt(2): drains g3(t)
//   P2 vmcnt(4): no-op (3 in flight)             P3 vmcnt(6): no-op (5 in flight)
// Never drains to 0; every group has >=2-phase issue->read slack.
#define QKV_M 4096
#define QKV_N 3072
#define QKV_K 1024
#define QKV_BN 192
#define QKV_NT (QKV_K / 64)

__global__ __launch_bounds__(512, 2) void gemm_qkv_8ph(const unsigned short* __restrict__ A,
                                                        const unsigned short* __restrict__ B,
                                                        unsigned short* __restrict__ C) {
    __shared__ __align__(16) unsigned short As[2][256][64];      // 64 KB
    __shared__ __align__(16) unsigned short Bs[2][QKV_BN][64];   // 48 KB

    const int tid  = threadIdx.x;
    const int w    = tid >> 6;        // wave 0..7
    const int lane = tid & 63;
    const int quad = lane >> 4;
    const int lcol = lane & 15;
    const int wr   = w >> 2;          // 0..1  (M half: 128 rows)
    const int wc   = w & 3;           // 0..3  (N quarter: 48 cols)

    // XCD-contiguous swizzle: 256 blocks = 8 XCDs x 32
    const int f  = blockIdx.x;
    const int wg = (f & 7) * 32 + (f >> 3);
    const int tn = (wg & 15) * QKV_BN;    // 3072/192 = 16
    const int tm = (wg >> 4) * 256;       // 4096/256 = 16

    const int srow8 = lane >> 3;      // staging: row within 8-row block
    const int sj    = lane & 7;       // staging: 16B chunk within row

    // stage A-group mh (rows {mh*64..+64} u {128+mh*64..+64}) of K-tile kt into buf
    auto stageA = [&](int buf, int kt, int mh) {
#pragma unroll
        for (int c = 0; c < 2; ++c) {
            const int r0 = mh * 64 + c * 128 + w * 8;
            const int r  = r0 + srow8;
            gload_lds16(A + (size_t)(tm + r) * QKV_K + kt * 64 + ((sj ^ (r & 7)) * 8),
                        &As[buf][r0][0]);
        }
    };
    // stage B rows 0-127 (2 gloads)
    auto stageB01 = [&](int buf, int kt) {
#pragma unroll
        for (int c = 0; c < 2; ++c) {
            const int r0 = c * 64 + w * 8;
            const int r  = r0 + srow8;
            gload_lds16(B + (size_t)(tn + r) * QKV_K + kt * 64 + ((sj ^ (r & 7)) * 8),
                        &Bs[buf][r0][0]);
        }
    };
    // stage B rows 128-191 (1 gload)
    auto stageB2 = [&](int buf, int kt) {
        const int r0 = 128 + w * 8;
        const int r  = r0 + srow8;
        gload_lds16(B + (size_t)(tn + r) * QKV_K + kt * 64 + ((sj ^ (r & 7)) * 8),
                    &Bs[buf][r0][0]);
    };

    floatx4 acc[8][3];
#pragma unroll
    for (int i = 0; i < 8; ++i)
#pragma unroll
        for (int j = 0; j < 3; ++j) acc[i][j] = (floatx4){0.f, 0.f, 0.f, 0.f};

    // phase (kk, mh): A-half x all-B at k-slice kk; 7 ds_read_b128 + 12 MFMA
    auto do_phase = [&](int buf, auto vmc, auto kkc, auto mhc, auto stager) {
        constexpr int VM = decltype(vmc)::value;
        constexpr int kk = decltype(kkc)::value;
        constexpr int mh = decltype(mhc)::value;
        if constexpr (VM == 2)      asm volatile("s_waitcnt vmcnt(2)" ::: "memory");
        else if constexpr (VM == 4) asm volatile("s_waitcnt vmcnt(4)" ::: "memory");
        else                        asm volatile("s_waitcnt vmcnt(6)" ::: "memory");
        __builtin_amdgcn_s_barrier();
        asm volatile("" ::: "memory");          // no LDS reads above the barrier
        short8 a[4], b[3];
#pragma unroll
        for (int i = 0; i < 4; ++i) {
            const int r = wr * 128 + mh * 64 + i * 16 + lcol;
            a[i] = *(const short8*)&As[buf][r][((kk * 4 + quad) ^ (r & 7)) * 8];
        }
#pragma unroll
        for (int j = 0; j < 3; ++j) {
            const int r = wc * 48 + j * 16 + lcol;
            b[j] = *(const short8*)&Bs[buf][r][((kk * 4 + quad) ^ (r & 7)) * 8];
        }
        stager();
        __builtin_amdgcn_s_setprio(1);
#pragma unroll
        for (int i = 0; i < 4; ++i)
#pragma unroll
            for (int j = 0; j < 3; ++j)
                acc[mh * 4 + i][j] = __builtin_amdgcn_mfma_f32_16x16x32_bf16(
                    a[i], b[j], acc[mh * 4 + i][j], 0, 0, 0);
        __builtin_amdgcn_s_setprio(0);
    };

    // prologue: tile 0 -> buf 0, staging order B01 B2 A0 A1 (7 loads)
    stageB01(0, 0); stageB2(0, 0); stageA(0, 0, 0); stageA(0, 0, 1);

    for (int t = 0; t < QKV_NT; ++t) {
        const int buf = t & 1, nb = buf ^ 1;
        const int kn = (t + 1 == QKV_NT) ? 0 : t + 1;   // wrap: dead restage keeps invariant
        do_phase(buf, IC<2>{}, IC<0>{}, IC<0>{}, [&] { stageB01(nb, kn); });
        do_phase(buf, IC<2>{}, IC<0>{}, IC<1>{}, [&] { stageB2(nb, kn); });
        do_phase(buf, IC<4>{}, IC<1>{}, IC<0>{}, [&] { stageA(nb, kn, 0); });
        do_phase(buf, IC<6>{}, IC<1>{}, IC<1>{}, [&] { stageA(nb, kn, 1); });
    }

    // epilogue: C-write (bf16)
#pragma unroll
    for (int i = 0; i < 8; ++i) {
#pragma unroll
        for (int rr = 0; rr < 4; ++rr) {
            const int row = tm + wr * 128 + i * 16 + quad * 4 + rr;
#pragma unroll
            for (int jf = 0; jf < 3; ++jf) {
                const int col = tn + wc * 48 + jf * 16 + lcol;
                C[(size_t)row * QKV_N + col] = f2bf(acc[i][jf][rr]);
            }
        }
    }
}

// ---------------- out-proj GEMM: 128x128 tile, 3-buffer, ONE barrier per K-tile ----
// The 4-phase form did only 4 MFMA/wave between barriers (barrier-dominated, ~same
// as the m97 version it replaced). Here: per K-tile {vmcnt(4) [drains tile t, leaves
// t+1 in flight]; s_barrier; stage tile t+2 (4 gloads); 12 ds_read; 16 MFMA}.
// Barriers 64 -> 16. WAR: buf[(t+2)%3] last read at tile t-1; those reads retired
// before barrier t (results consumed pre-arrival); stage issued after barrier t.
// RAW: tile staged 2 tile-times before its vmcnt-enforced drain.
#define OUT_M 4096
#define OUT_N 1024
#define OUT_K 1024
#define OUT_NT (OUT_K / 64)

__global__ __launch_bounds__(512, 1) void gemm_out_3buf(const unsigned short* __restrict__ A,
                                                        const unsigned short* __restrict__ B,
                                                        const float* __restrict__ bias,
                                                        float* __restrict__ C) {
    __shared__ __align__(16) unsigned short As[3][128][64];   // 48 KB
    __shared__ __align__(16) unsigned short Bs[3][128][64];   // 48 KB

    const int tid  = threadIdx.x;
    const int w    = tid >> 6;        // wave 0..7
    const int lane = tid & 63;
    const int quad = lane >> 4;
    const int lcol = lane & 15;
    const int wr   = w >> 2;          // 0..1  (M half: 64 rows)
    const int wc   = w & 3;           // 0..3  (N quarter: 32 cols)

    // XCD-contiguous swizzle: 256 blocks = 8 XCDs x 32
    const int f  = blockIdx.x;
    const int wg = (f & 7) * 32 + (f >> 3);
    const int tn = (wg & 7) * 128;    // OUT_N/128 = 8
    const int tm = (wg >> 3) * 128;   // OUT_M/128 = 32

    const int srow8 = lane >> 3;
    const int sj    = lane & 7;

    // stage whole 128x64 A-tile and B-tile of K-tile kt into buf (4 gloads)
    auto stage = [&](int buf, int kt) {
#pragma unroll
        for (int g = 0; g < 2; ++g) {
            const int r0 = g * 64 + w * 8;
            const int r  = r0 + srow8;
            gload_lds16(A + (size_t)(tm + r) * OUT_K + kt * 64 + ((sj ^ (r & 7)) * 8),
                        &As[buf][r0][0]);
        }
#pragma unroll
        for (int g = 0; g < 2; ++g) {
            const int r0 = g * 64 + w * 8;
            const int r  = r0 + srow8;
            gload_lds16(B + (size_t)(tn + r) * OUT_K + kt * 64 + ((sj ^ (r & 7)) * 8),
                        &Bs[buf][r0][0]);
        }
    };

    floatx4 acc[4][2];
#pragma unroll
    for (int i = 0; i < 4; ++i)
#pragma unroll
        for (int j = 0; j < 2; ++j) acc[i][j] = (floatx4){0.f, 0.f, 0.f, 0.f};

    // prologue: tiles 0,1 -> bufs 0,1 (8 loads in flight)
    stage(0, 0);
    stage(1, 1);

    int cb = 0;
    for (int t = 0; t < OUT_NT; ++t) {
        asm volatile("s_waitcnt vmcnt(4)" ::: "memory");   // drains tile t, leaves t+1
        __builtin_amdgcn_s_barrier();
        asm volatile("" ::: "memory");
        const int kt2 = (t + 2 < OUT_NT) ? t + 2 : t - 14; // wrap: dead restage
        int sb = cb + 2; if (sb >= 3) sb -= 3;
        stage(sb, kt2);

        short8 a[2][2][2], bfr[2][2];                      // [mh][i][kk], [j][kk]
#pragma unroll
        for (int mh = 0; mh < 2; ++mh)
#pragma unroll
            for (int i = 0; i < 2; ++i)
#pragma unroll
                for (int kk = 0; kk < 2; ++kk) {
                    const int r = wr * 64 + mh * 32 + i * 16 + lcol;
                    a[mh][i][kk] = *(const short8*)&As[cb][r][((kk * 4 + quad) ^ (r & 7)) * 8];
                }
#pragma unroll
        for (int j = 0; j < 2; ++j)
#pragma unroll
            for (int kk = 0; kk < 2; ++kk) {
                const int r = wc * 32 + j * 16 + lcol;
                bfr[j][kk] = *(const short8*)&Bs[cb][r][((kk * 4 + quad) ^ (r & 7)) * 8];
            }
        __builtin_amdgcn_s_setprio(1);
#pragma unroll
        for (int kk = 0; kk < 2; ++kk)
#pragma unroll
            for (int mh = 0; mh < 2; ++mh)
#pragma unroll
                for (int i = 0; i < 2; ++i)
#pragma unroll
                    for (int j = 0; j < 2; ++j)
                        acc[mh * 2 + i][j] = __builtin_amdgcn_mfma_f32_16x16x32_bf16(
                            a[mh][i][kk], bfr[j][kk], acc[mh * 2 + i][j], 0, 0, 0);
        __builtin_amdgcn_s_setprio(0);

        cb = cb + 1; if (cb == 3) cb = 0;
    }

    // epilogue: fp32 C-write + bias
#pragma unroll
    for (int i = 0; i < 4; ++i) {
#pragma unroll
        for (int rr = 0; rr < 4; ++rr) {
            const int row = tm + wr * 64 + i * 16 + quad * 4 + rr;
#pragma unroll
            for (int j = 0; j < 2; ++j) {
                const int col = tn + wc * 32 + j * 16 + lcol;
                C[(size_t)row * OUT_N + col] = acc[i][j][rr] + bias[col];
            }
        }
    }
}

// ---------------- fused RoPE pack (Q*0.125*log2e, K) + sigma-permuted V transpose ---
// Key u within each 64-tile is stored at column c(u) = (u&48) | (8*((u>>2)&1) + (u&3)
// + 4*((u>>3)&1)) so PV's A-operand (= S^T C-regs) and B-operand (V) agree on the
// 32x32x16 MFMA k-index mapping. RoPE q/k pair loads vectorized to single u32 (G13).
__global__ __launch_bounds__(256) void rope_vtrans(const unsigned short* __restrict__ qkvb,
                                                   unsigned short* __restrict__ Qb,
                                                   unsigned short* __restrict__ Kb,
                                                   unsigned short* __restrict__ Vtg) {
    const int st = blockIdx.x, h = blockIdx.y, b = blockIdx.z;
    const int tid = threadIdx.x;
    const int s0 = st * 64;

    // ---- RoPE on Q,K ----
    const int i  = tid & 31;
    const int r0 = tid >> 5;                   // 0..7
    const float inv_freq = exp2f(-(2.0f * (float)i / (float)DK) * log2f(50.0f));
    const float QSCALE = 0.125f * 1.44269504f; // 1/sqrt(dk) * log2(e)
#pragma unroll
    for (int pass = 0; pass < 8; ++pass) {
        const int s = s0 + r0 + pass * 8;
        const size_t in_base = ((size_t)(b * SEQ + s)) * (3 * D_MODEL) + h * DK + 2 * i;
        const unsigned int qin = *(const unsigned int*)&qkvb[in_base];
        const unsigned int kin = *(const unsigned int*)&qkvb[in_base + D_MODEL];
        const float q0 = bf2f((unsigned short)(qin & 0xFFFFu));
        const float q1 = bf2f((unsigned short)(qin >> 16));
        const float k0 = bf2f((unsigned short)(kin & 0xFFFFu));
        const float k1 = bf2f((unsigned short)(kin >> 16));
        float sn, cs;
        __sincosf((float)s * inv_freq, &sn, &cs);
        const size_t ob = (((size_t)(b * NHEADS + h)) * SEQ + s) * DK + 2 * i;
        const unsigned int qw = (unsigned int)f2bf((q0 * cs - q1 * sn) * QSCALE)
                              | ((unsigned int)f2bf((q1 * cs + q0 * sn) * QSCALE) << 16);
        const unsigned int kw = (unsigned int)f2bf(k0 * cs - k1 * sn)
                              | ((unsigned int)f2bf(k1 * cs + k0 * sn) << 16);
        *(unsigned int*)&Qb[ob] = qw;
        *(unsigned int*)&Kb[ob] = kw;
    }

    // ---- V transpose with sigma column permutation ----
    __shared__ unsigned short Lt[64][65];
    const int r = tid >> 3;                    // 0..31 (key within tile)
    const int c = (tid & 7) * 8;
    const size_t in_row = ((size_t)(b * SEQ + s0 + r)) * (3 * D_MODEL) + 2 * D_MODEL + h * DK + c;
    const ushort8 v0 = *(const ushort8*)&qkvb[in_row];
    const ushort8 v1 = *(const ushort8*)&qkvb[in_row + (size_t)32 * (3 * D_MODEL)];
    const int u0 = r, u1 = r + 32;
    const int kc0 = (u0 & 48) | (8 * ((u0 >> 2) & 1) + (u0 & 3) + 4 * ((u0 >> 3) & 1));
    const int kc1 = (u1 & 48) | (8 * ((u1 >> 2) & 1) + (u1 & 3) + 4 * ((u1 >> 3) & 1));
#pragma unroll
    for (int j = 0; j < 8; ++j) Lt[c + j][kc0] = v0[j];
#pragma unroll
    for (int j = 0; j < 8; ++j) Lt[c + j][kc1] = v1[j];
    __syncthreads();
    const size_t bh = (size_t)(b * NHEADS + h);
    ushort8 o0, o1;
#pragma unroll
    for (int j = 0; j < 8; ++j) { o0[j] = Lt[r][c + j]; o1[j] = Lt[r + 32][c + j]; }
    unsigned short* orow = Vtg + (bh * DK + r) * SEQ + s0 + c;   // r = d-row
    *(ushort8*)orow = o0;
    *(ushort8*)(orow + (size_t)32 * SEQ) = o1;
}

// ---------------- flash attention: QTILE=128, 8 waves, double-buffered K/V LDS ----
// Measured-best flash form (r3/r9: 43.6-44.0us). Local optimum — deferred-PV 3-buf,
// 64qx32k LDS-reuse, and async gload_lds counted-vmcnt all measured WORSE
// (47.4/47.8/50.5). Do not re-attempt piecemeal grafts on this structure.
#define LDW 72

__global__ __launch_bounds__(512, 4) void flash_attn(const unsigned short* __restrict__ Qb,
                                                     const unsigned short* __restrict__ Kb,
                                                     const unsigned short* __restrict__ Vtg,
                                                     unsigned short* __restrict__ attnb) {
    const int tid  = threadIdx.x;
    const int wave = tid >> 6;
    const int lane = tid & 63;
    const int l31  = lane & 31;
    const int lh   = lane >> 5;               // lane half (k-group)
    const int mh2  = wave & 3;                // m-quarter (32 q rows of 128)
    const int kh   = wave >> 2;               // key-half (32 keys of 64)
    const int kb   = kh * 32;

    // XCD-grouping swizzle: 512 blocks, assume round-robin f%8 -> XCD
    const int f  = blockIdx.x + gridDim.x * (blockIdx.y + gridDim.y * blockIdx.z);
    const int w  = (f & 7) * 64 + (f >> 3);   // bijective (512 % 8 == 0)
    const int qt = w & 15;                    // 0..15 (tiles of 128 queries)
    const int h  = (w >> 4) & 15;
    const int b  = w >> 8;

    __shared__ __align__(16) unsigned char smem[36864];          // 2 x (Ks 9216 + Vt 9216)
    unsigned short (*Ks0)[LDW] = (unsigned short (*)[LDW])(smem);
    unsigned short (*Vt0)[LDW] = (unsigned short (*)[LDW])(smem +  9216);
    unsigned short (*Ks1)[LDW] = (unsigned short (*)[LDW])(smem + 18432);
    unsigned short (*Vt1)[LDW] = (unsigned short (*)[LDW])(smem + 27648);
    // epilogue overlays (staging dead): 128*68*4 + 2*128*4 = 35840 <= 36864
    float (*Ored)[68] = (float (*)[68])smem;
    float* lred0 = (float*)(smem + 34816);
    float* lred1 = lred0 + 128;

    const size_t bh = (size_t)(b * NHEADS + h);
    const unsigned short* Qg = Qb + (bh * SEQ + (size_t)qt * QTILE) * DK;
    const unsigned short* Kg = Kb + bh * SEQ * DK;
    const unsigned short* Vg = Vtg + bh * (size_t)DK * SEQ;

    // Q as B-operand: B[n=m=lane&31][k=lh*8+j]; frag t covers dk 16t..16t+15
    short8 qf[4];
#pragma unroll
    for (int t = 0; t < 4; ++t)
        qf[t] = *(const short8*)&Qg[(size_t)(mh2 * 32 + l31) * DK + t * 16 + lh * 8];

    // staging: 512 threads, each 1 short8 into Ks and 1 into Vt (64 rows x 64 cols)
    const int strow = tid >> 3;               // 0..63
    const int stcol = (tid & 7) * 8;
    const unsigned short* kg = &Kg[(size_t)strow * DK + stcol];
    const unsigned short* vg = &Vg[(size_t)strow * SEQ + stcol];

    short8 kr = *(const short8*)&kg[0];
    short8 vr = *(const short8*)&vg[0];

    floatx16 oacc[2];
    oacc[0] = (floatx16)(0.f);
    oacc[1] = (floatx16)(0.f);
    float lp = 0.f;                           // scalar l partial: query m = mh2*32+l31

    // diagonal tile for this wave: key global == q global  <=>  kt + kb == qt*128 + mh2*32
    const int diagkt = qt * QTILE + mh2 * 32 - kb;

    auto compute = [&](unsigned short (*Ks)[LDW], unsigned short (*Vt)[LDW], int kt) {
        // ---- S^T = K Q^T : C[row=key scatter][col=m=lane&31], 4 MFMAs ----
        floatx16 sc = (floatx16)(0.f);
        __builtin_amdgcn_s_setprio(1);
#pragma unroll
        for (int t = 0; t < 4; ++t) {
            const short8 kf = *(short8*)&Ks[kb + l31][t * 16 + lh * 8];
            sc = __builtin_amdgcn_mfma_f32_32x32x16_bf16(kf, qf[t], sc, 0, 0, 0);
        }
        __builtin_amdgcn_s_setprio(0);

        // ---- diagonal mask ----
        if (kt == diagkt) {
#pragma unroll
            for (int r = 0; r < 16; ++r) {
                const int key_loc = (r & 3) + 8 * (r >> 2) + 4 * lh;
                if (key_loc == l31) sc[r] = -1e30f;
            }
        }

        // ---- P = exp2(S^T): native v_exp_f32 + v_perm trunc pack; lp accumulates ----
        short8 pf0, pf1;
        {
            union { unsigned int u[4]; short8 s8; } a, c;
#pragma unroll
            for (int d = 0; d < 4; ++d) {
                const float e0 = __builtin_amdgcn_exp2f(sc[2 * d]);
                const float e1 = __builtin_amdgcn_exp2f(sc[2 * d + 1]);
                a.u[d] = __builtin_amdgcn_perm(fau(e1), fau(e0), 0x07060302u);
                const float f0 = __builtin_amdgcn_exp2f(sc[8 + 2 * d]);
                const float f1 = __builtin_amdgcn_exp2f(sc[8 + 2 * d + 1]);
                c.u[d] = __builtin_amdgcn_perm(fau(f1), fau(f0), 0x07060302u);
                lp += (e0 + e1) + (f0 + f1);
            }
            pf0 = a.s8;
            pf1 = c.s8;
        }

        // ---- O += P V  (V pre-permuted so k-indices align) ----
        __builtin_amdgcn_s_setprio(1);
#pragma unroll
        for (int nd = 0; nd < 2; ++nd) {
            const short8 vfa = *(short8*)&Vt[nd * 32 + l31][kb + lh * 8];        // keys 0..15
            const short8 vfb = *(short8*)&Vt[nd * 32 + l31][kb + 16 + lh * 8];   // keys 16..31
            oacc[nd] = __builtin_amdgcn_mfma_f32_32x32x16_bf16(pf0, vfa, oacc[nd], 0, 0, 0);
            oacc[nd] = __builtin_amdgcn_mfma_f32_32x32x16_bf16(pf1, vfb, oacc[nd], 0, 0, 0);
        }
        __builtin_amdgcn_s_setprio(0);
    };

    for (int kt = 0; kt < SEQ; kt += 128) {
        // ---- phase A: buffer 0, keys [kt, kt+64) ----
        *(short8*)&Ks0[strow][stcol] = kr;
        *(short8*)&Vt0[strow][stcol] = vr;
        __syncthreads();
        kr = *(const short8*)&kg[(size_t)(kt + 64) * DK];
        vr = *(const short8*)&vg[kt + 64];
        compute(Ks0, Vt0, kt);

        // ---- phase B: buffer 1, keys [kt+64, kt+128) ----
        *(short8*)&Ks1[strow][stcol] = kr;
        *(short8*)&Vt1[strow][stcol] = vr;
        __syncthreads();
        const int ktn = (kt + 128 < SEQ) ? kt + 128 : 0;
        kr = *(const short8*)&kg[(size_t)ktn * DK];
        vr = *(const short8*)&vg[ktn];
        compute(Ks1, Vt1, kt + 64);
    }

    // ---- l: combine the two lane-halves (same m, disjoint keys) ----
    const float lptot = lp + __shfl_xor(lp, 32, 64);

    // ---- cross-wave (key-half) reduction through LDS overlay ----
    __syncthreads();                          // staging buffers dead
    if (lh == 0) {
        if (kh == 0) lred0[mh2 * 32 + l31] = lptot;
        else         lred1[mh2 * 32 + l31] = lptot;
    }
    if (kh == 1) {
#pragma unroll
        for (int r = 0; r < 16; ++r) {
            const int m = mh2 * 32 + (r & 3) + 8 * (r >> 2) + 4 * lh;
            Ored[m][l31]      = oacc[0][r];
            Ored[m][32 + l31] = oacc[1][r];
        }
    }
    __syncthreads();
    if (kh == 0) {
        unsigned short* obase = attnb + ((size_t)b * SEQ + (size_t)qt * QTILE) * D_MODEL + h * DK;
        // 1.001953125 = 1/(1 - 2^-9): compensates mean truncation bias of bf16 P
        // (numerator uses trunc(P), denominator uses full-precision sums).
#pragma unroll
        for (int r = 0; r < 16; ++r) {
            const int m = mh2 * 32 + (r & 3) + 8 * (r >> 2) + 4 * lh;
            const float inv = 1.001953125f / (lred0[m] + lred1[m]);
            const float v0 = (oacc[0][r] + Ored[m][l31]) * inv;
            const float v1 = (oacc[1][r] + Ored[m][32 + l31]) * inv;
            obase[(size_t)m * D_MODEL + l31]      = f2bf(v0);
            obase[(size_t)m * D_MODEL + 32 + l31] = f2bf(v1);
        }
    }
}

extern "C" void kernel_launch(void* const* d_in, const int* in_sizes, int n_in,
                              void* d_out, int out_size, void* d_ws, size_t ws_size,
                              hipStream_t stream) {
    const float* x     = (const float*)d_in[0];
    const float* w_qkv = (const float*)d_in[1];
    const float* w_out = (const float*)d_in[2];
    const float* b_out = (const float*)d_in[3];
    float* out = (float*)d_out;

    const int M = BATCH * SEQ;                                   // 4096
    const size_t X_ELEMS    = (size_t)M * D_MODEL;
    const size_t WQKV_ELEMS = (size_t)3 * D_MODEL * D_MODEL;
    const size_t WOUT_ELEMS = (size_t)D_MODEL * D_MODEL;
    const size_t QKV_ELEMS  = (size_t)M * 3 * D_MODEL;
    const size_t HEAD_ELEMS = (size_t)BATCH * NHEADS * SEQ * DK;

    unsigned short* xb    = (unsigned short*)d_ws;
    unsigned short* wqkvb = xb + X_ELEMS;
    unsigned short* woutb = wqkvb + WQKV_ELEMS;
    unsigned short* qkvb  = woutb + WOUT_ELEMS;
    unsigned short* Qb    = qkvb + QKV_ELEMS;
    unsigned short* Kb    = Qb + HEAD_ELEMS;
    unsigned short* Vtg   = Kb + HEAD_ELEMS;                     // [B,H,64,S] sigma-permuted
    unsigned short* attnb = Vtg + HEAD_ELEMS;

    // 0) pack all inputs to bf16
    pack_all<<<(X8 + W8 + O8 + 255) / 256, 256, 0, stream>>>(x, w_qkv, w_out, xb, wqkvb, woutb);

    // 1) qkvb = xb @ wqkvb^T  (256x192 8-phase pipeline, 256 blocks = 1/CU)
    gemm_qkv_8ph<<<(QKV_M / 256) * (QKV_N / QKV_BN), 512, 0, stream>>>(xb, wqkvb, qkvb);

    // 2) RoPE pack + sigma-permuted V transpose
    {
        dim3 grid(SEQ / 64, NHEADS, BATCH);
        rope_vtrans<<<grid, 256, 0, stream>>>(qkvb, Qb, Kb, Vtg);
    }
    // 3) flash attention (QTILE=128, 8 waves, dbuf K/V — measured-best form)
    {
        dim3 grid(SEQ / QTILE, NHEADS, BATCH);
        flash_attn<<<grid, 512, 0, stream>>>(Qb, Kb, Vtg, attnb);
    }
    // 4) out = attnb @ woutb^T + b_out  (128^2 3-buffer, 1 barrier/K-tile, 256 blocks)
    gemm_out_3buf<<<(OUT_M / 128) * (OUT_N / 128), 512, 0, stream>>>(attnb, woutb, b_out, out);
}

// Round 11
// 169.464 us; speedup vs baseline: 1.1067x; 1.0315x over previous
//
#include <hip/hip_runtime.h>
#include <hip/hip_bf16.h>
#include <math.h>
#include <type_traits>

#define D_MODEL 1024
#define NHEADS  16
#define DK      64
#define SEQ     2048
#define BATCH   2
#define QTILE   128

typedef __attribute__((ext_vector_type(8)))  short  short8;
typedef __attribute__((ext_vector_type(8)))  unsigned short ushort8;
typedef __attribute__((ext_vector_type(4)))  float  floatx4;
typedef __attribute__((ext_vector_type(16))) float  floatx16;

template <int N> using IC = std::integral_constant<int, N>;

__device__ __forceinline__ unsigned short f2bf(float f) {      // RNE
    union { float f; unsigned int u; } v; v.f = f;
    unsigned int u = v.u;
    return (unsigned short)((u + 0x7FFFu + ((u >> 16) & 1u)) >> 16);
}
__device__ __forceinline__ float bf2f(unsigned short u) {
    union { unsigned int u; float f; } v; v.u = ((unsigned int)u) << 16;
    return v.f;
}
__device__ __forceinline__ unsigned int fau(float f) {
    union { float f; unsigned int u; } v; v.f = f; return v.u;
}

// async global->LDS, 16B per lane. LDS dest = wave-uniform base + lane*16.
__device__ __forceinline__ void gload_lds16(const unsigned short* g, unsigned short* l) {
    __builtin_amdgcn_global_load_lds((__attribute__((address_space(1))) const void*)g,
                                     (__attribute__((address_space(3))) void*)l,
                                     16, 0, 0);
}

// ---------------- fused fp32 -> bf16 pack of x, w_qkv, w_out ----------------
#define X8 ((BATCH * SEQ * D_MODEL) / 8)
#define W8 ((3 * D_MODEL * D_MODEL) / 8)
#define O8 ((D_MODEL * D_MODEL) / 8)
__global__ __launch_bounds__(256) void pack_all(const float* __restrict__ x,
                                                const float* __restrict__ wq,
                                                const float* __restrict__ wo,
                                                unsigned short* __restrict__ xb,
                                                unsigned short* __restrict__ wqb,
                                                unsigned short* __restrict__ wob) {
    const int t = blockIdx.x * blockDim.x + threadIdx.x;
    const float* src; unsigned short* dst; int idx;
    if (t < X8)           { src = x;  dst = xb;  idx = t; }
    else if (t < X8 + W8) { src = wq; dst = wqb; idx = t - X8; }
    else if (t < X8 + W8 + O8) { src = wo; dst = wob; idx = t - X8 - W8; }
    else return;
    const float4 a = ((const float4*)src)[2 * idx];
    const float4 b = ((const float4*)src)[2 * idx + 1];
    short8 o;
    o[0] = (short)f2bf(a.x); o[1] = (short)f2bf(a.y);
    o[2] = (short)f2bf(a.z); o[3] = (short)f2bf(a.w);
    o[4] = (short)f2bf(b.x); o[5] = (short)f2bf(b.y);
    o[6] = (short)f2bf(b.z); o[7] = (short)f2bf(b.w);
    ((short8*)dst)[idx] = o;
}

// ---------------- QKV GEMM: 256x192 tile, BK=64, 8-phase counted-vmcnt pipeline ----
// SNAKE phase order (k0,m0),(k0,m1),(k1,m1),(k1,m0): B frags loaded only at kk-change
// (P0,P2) and reused across the mh pair -> 22 ds_read_b128/wave/tile (was 28).
// Per-acc-element accumulation order unchanged (kk0 then kk1) -> bit-identical.
// Staging groups per tile: g0=B rows 0-127 (2 gloads), g1=B 128-191 (1), g2=A mh0 (2),
// g3=A mh1 (2), issued at P0..P3. vmcnt trace (steady state, in-flight at entry):
//   P0: 7 -> vmcnt(2) retires g0,g1,g2(t)   P1: 4 -> vmcnt(2) retires g3(t)
//   P2: 3 -> vmcnt(4) no-op                 P3: 5 -> vmcnt(6) no-op
// Never drains to 0; >=2-phase slack on all groups (A1 staged P3(t-1), read P1(t)).
// SUPER-TILE XCD swizzle: each XCD owns two 4x4 (tm,tn) super-tiles -> per-XCD L2
// working set 4 A-panels + 4 B-panels = 3.5MB <= 4MB (old tn-striped swizzle streamed
// all 16 B-panels = 6MB through each XCD's L2 -> ~98MB of B HBM traffic).
#define QKV_M 4096
#define QKV_N 3072
#define QKV_K 1024
#define QKV_BN 192
#define QKV_NT (QKV_K / 64)

__global__ __launch_bounds__(512, 2) void gemm_qkv_8ph(const unsigned short* __restrict__ A,
                                                        const unsigned short* __restrict__ B,
                                                        unsigned short* __restrict__ C) {
    __shared__ __align__(16) unsigned short As[2][256][64];      // 64 KB
    __shared__ __align__(16) unsigned short Bs[2][QKV_BN][64];   // 48 KB

    const int tid  = threadIdx.x;
    const int w    = tid >> 6;        // wave 0..7
    const int lane = tid & 63;
    const int quad = lane >> 4;
    const int lcol = lane & 15;
    const int wr   = w >> 2;          // 0..1  (M half: 128 rows)
    const int wc   = w & 3;           // 0..3  (N quarter: 48 cols)

    // super-tile swizzle: 256 blocks = 8 XCDs x 2 super-tiles x (4tm x 4tn)
    const int f  = blockIdx.x;
    const int xc = f & 7;
    const int j  = f >> 3;                     // 0..31
    const int st = xc * 2 + (j >> 4);          // super-tile 0..15
    const int i4 = j & 15;
    const int tm = ((st >> 2) * 4 + (i4 >> 2)) * 256;      // 16 tm values
    const int tn = ((st & 3) * 4 + (i4 & 3)) * QKV_BN;     // 16 tn values

    const int srow8 = lane >> 3;      // staging: row within 8-row block
    const int sj    = lane & 7;       // staging: 16B chunk within row

    // stage A-group mh (rows {mh*64..+64} u {128+mh*64..+64}) of K-tile kt into buf
    auto stageA = [&](int buf, int kt, int mh) {
#pragma unroll
        for (int c = 0; c < 2; ++c) {
            const int r0 = mh * 64 + c * 128 + w * 8;
            const int r  = r0 + srow8;
            gload_lds16(A + (size_t)(tm + r) * QKV_K + kt * 64 + ((sj ^ (r & 7)) * 8),
                        &As[buf][r0][0]);
        }
    };
    // stage B rows 0-127 (2 gloads)
    auto stageB01 = [&](int buf, int kt) {
#pragma unroll
        for (int c = 0; c < 2; ++c) {
            const int r0 = c * 64 + w * 8;
            const int r  = r0 + srow8;
            gload_lds16(B + (size_t)(tn + r) * QKV_K + kt * 64 + ((sj ^ (r & 7)) * 8),
                        &Bs[buf][r0][0]);
        }
    };
    // stage B rows 128-191 (1 gload)
    auto stageB2 = [&](int buf, int kt) {
        const int r0 = 128 + w * 8;
        const int r  = r0 + srow8;
        gload_lds16(B + (size_t)(tn + r) * QKV_K + kt * 64 + ((sj ^ (r & 7)) * 8),
                    &Bs[buf][r0][0]);
    };

    floatx4 acc[8][3];
#pragma unroll
    for (int i = 0; i < 8; ++i)
#pragma unroll
        for (int jj = 0; jj < 3; ++jj) acc[i][jj] = (floatx4){0.f, 0.f, 0.f, 0.f};

    short8 breg[3];                   // B frags persist across the mh pair of a kk

    // phase (kk, mh): A-half x all-B at k-slice kk; 4 (+3 if LOADB) ds_read + 12 MFMA
    auto do_phase = [&](int buf, auto vmc, auto kkc, auto mhc, auto ldbc, auto stager) {
        constexpr int VM    = decltype(vmc)::value;
        constexpr int kk    = decltype(kkc)::value;
        constexpr int mh    = decltype(mhc)::value;
        constexpr int LOADB = decltype(ldbc)::value;
        if constexpr (VM == 2)      asm volatile("s_waitcnt vmcnt(2)" ::: "memory");
        else if constexpr (VM == 4) asm volatile("s_waitcnt vmcnt(4)" ::: "memory");
        else                        asm volatile("s_waitcnt vmcnt(6)" ::: "memory");
        __builtin_amdgcn_s_barrier();
        asm volatile("" ::: "memory");          // no LDS reads above the barrier
        short8 a[4];
#pragma unroll
        for (int i = 0; i < 4; ++i) {
            const int r = wr * 128 + mh * 64 + i * 16 + lcol;
            a[i] = *(const short8*)&As[buf][r][((kk * 4 + quad) ^ (r & 7)) * 8];
        }
        if constexpr (LOADB) {
#pragma unroll
            for (int jj = 0; jj < 3; ++jj) {
                const int r = wc * 48 + jj * 16 + lcol;
                breg[jj] = *(const short8*)&Bs[buf][r][((kk * 4 + quad) ^ (r & 7)) * 8];
            }
        }
        stager();
        __builtin_amdgcn_s_setprio(1);
#pragma unroll
        for (int i = 0; i < 4; ++i)
#pragma unroll
            for (int jj = 0; jj < 3; ++jj)
                acc[mh * 4 + i][jj] = __builtin_amdgcn_mfma_f32_16x16x32_bf16(
                    a[i], breg[jj], acc[mh * 4 + i][jj], 0, 0, 0);
        __builtin_amdgcn_s_setprio(0);
    };

    // prologue: tile 0 -> buf 0, staging order B01 B2 A0 A1 (7 loads)
    stageB01(0, 0); stageB2(0, 0); stageA(0, 0, 0); stageA(0, 0, 1);

    for (int t = 0; t < QKV_NT; ++t) {
        const int buf = t & 1, nb = buf ^ 1;
        const int kn = (t + 1 == QKV_NT) ? 0 : t + 1;   // wrap: dead restage keeps invariant
        do_phase(buf, IC<2>{}, IC<0>{}, IC<0>{}, IC<1>{}, [&] { stageB01(nb, kn); });
        do_phase(buf, IC<2>{}, IC<0>{}, IC<1>{}, IC<0>{}, [&] { stageB2(nb, kn); });
        do_phase(buf, IC<4>{}, IC<1>{}, IC<1>{}, IC<1>{}, [&] { stageA(nb, kn, 0); });
        do_phase(buf, IC<6>{}, IC<1>{}, IC<0>{}, IC<0>{}, [&] { stageA(nb, kn, 1); });
    }

    // epilogue: C-write (bf16)
#pragma unroll
    for (int i = 0; i < 8; ++i) {
#pragma unroll
        for (int rr = 0; rr < 4; ++rr) {
            const int row = tm + wr * 128 + i * 16 + quad * 4 + rr;
#pragma unroll
            for (int jf = 0; jf < 3; ++jf) {
                const int col = tn + wc * 48 + jf * 16 + lcol;
                C[(size_t)row * QKV_N + col] = f2bf(acc[i][jf][rr]);
            }
        }
    }
}

// ---------------- out-proj GEMM: 128x128 tile, 3-buffer, ONE barrier per K-tile ----
// Per K-tile: {vmcnt(4) [drains tile t, leaves t+1 in flight]; s_barrier; stage tile
// t+2 (4 gloads); 12 ds_read; 16 MFMA}. Barriers 64 -> 16. WAR: buf[(t+2)%3] last
// read at tile t-1; reads retired before barrier t; stage issued after barrier t.
#define OUT_M 4096
#define OUT_N 1024
#define OUT_K 1024
#define OUT_NT (OUT_K / 64)

__global__ __launch_bounds__(512, 1) void gemm_out_3buf(const unsigned short* __restrict__ A,
                                                        const unsigned short* __restrict__ B,
                                                        const float* __restrict__ bias,
                                                        float* __restrict__ C) {
    __shared__ __align__(16) unsigned short As[3][128][64];   // 48 KB
    __shared__ __align__(16) unsigned short Bs[3][128][64];   // 48 KB

    const int tid  = threadIdx.x;
    const int w    = tid >> 6;        // wave 0..7
    const int lane = tid & 63;
    const int quad = lane >> 4;
    const int lcol = lane & 15;
    const int wr   = w >> 2;          // 0..1  (M half: 64 rows)
    const int wc   = w & 3;           // 0..3  (N quarter: 32 cols)

    // XCD-contiguous swizzle: 256 blocks = 8 XCDs x 32 (per-XCD: 4 A-panels + all B = 3MB)
    const int f  = blockIdx.x;
    const int wg = (f & 7) * 32 + (f >> 3);
    const int tn = (wg & 7) * 128;    // OUT_N/128 = 8
    const int tm = (wg >> 3) * 128;   // OUT_M/128 = 32

    const int srow8 = lane >> 3;
    const int sj    = lane & 7;

    // stage whole 128x64 A-tile and B-tile of K-tile kt into buf (4 gloads)
    auto stage = [&](int buf, int kt) {
#pragma unroll
        for (int g = 0; g < 2; ++g) {
            const int r0 = g * 64 + w * 8;
            const int r  = r0 + srow8;
            gload_lds16(A + (size_t)(tm + r) * OUT_K + kt * 64 + ((sj ^ (r & 7)) * 8),
                        &As[buf][r0][0]);
        }
#pragma unroll
        for (int g = 0; g < 2; ++g) {
            const int r0 = g * 64 + w * 8;
            const int r  = r0 + srow8;
            gload_lds16(B + (size_t)(tn + r) * OUT_K + kt * 64 + ((sj ^ (r & 7)) * 8),
                        &Bs[buf][r0][0]);
        }
    };

    floatx4 acc[4][2];
#pragma unroll
    for (int i = 0; i < 4; ++i)
#pragma unroll
        for (int j = 0; j < 2; ++j) acc[i][j] = (floatx4){0.f, 0.f, 0.f, 0.f};

    // prologue: tiles 0,1 -> bufs 0,1 (8 loads in flight)
    stage(0, 0);
    stage(1, 1);

    int cb = 0;
    for (int t = 0; t < OUT_NT; ++t) {
        asm volatile("s_waitcnt vmcnt(4)" ::: "memory");   // drains tile t, leaves t+1
        __builtin_amdgcn_s_barrier();
        asm volatile("" ::: "memory");
        const int kt2 = (t + 2 < OUT_NT) ? t + 2 : t - 14; // wrap: dead restage
        int sb = cb + 2; if (sb >= 3) sb -= 3;
        stage(sb, kt2);

        short8 a[2][2][2], bfr[2][2];                      // [mh][i][kk], [j][kk]
#pragma unroll
        for (int mh = 0; mh < 2; ++mh)
#pragma unroll
            for (int i = 0; i < 2; ++i)
#pragma unroll
                for (int kk = 0; kk < 2; ++kk) {
                    const int r = wr * 64 + mh * 32 + i * 16 + lcol;
                    a[mh][i][kk] = *(const short8*)&As[cb][r][((kk * 4 + quad) ^ (r & 7)) * 8];
                }
#pragma unroll
        for (int j = 0; j < 2; ++j)
#pragma unroll
            for (int kk = 0; kk < 2; ++kk) {
                const int r = wc * 32 + j * 16 + lcol;
                bfr[j][kk] = *(const short8*)&Bs[cb][r][((kk * 4 + quad) ^ (r & 7)) * 8];
            }
        __builtin_amdgcn_s_setprio(1);
#pragma unroll
        for (int kk = 0; kk < 2; ++kk)
#pragma unroll
            for (int mh = 0; mh < 2; ++mh)
#pragma unroll
                for (int i = 0; i < 2; ++i)
#pragma unroll
                    for (int j = 0; j < 2; ++j)
                        acc[mh * 2 + i][j] = __builtin_amdgcn_mfma_f32_16x16x32_bf16(
                            a[mh][i][kk], bfr[j][kk], acc[mh * 2 + i][j], 0, 0, 0);
        __builtin_amdgcn_s_setprio(0);

        cb = cb + 1; if (cb == 3) cb = 0;
    }

    // epilogue: fp32 C-write + bias
#pragma unroll
    for (int i = 0; i < 4; ++i) {
#pragma unroll
        for (int rr = 0; rr < 4; ++rr) {
            const int row = tm + wr * 64 + i * 16 + quad * 4 + rr;
#pragma unroll
            for (int j = 0; j < 2; ++j) {
                const int col = tn + wc * 32 + j * 16 + lcol;
                C[(size_t)row * OUT_N + col] = acc[i][j][rr] + bias[col];
            }
        }
    }
}

// ---------------- fused RoPE pack (Q*0.125*log2e, K) + sigma-permuted V transpose ---
// Key u within each 64-tile is stored at column c(u) = (u&48) | (8*((u>>2)&1) + (u&3)
// + 4*((u>>3)&1)) so PV's A-operand (= S^T C-regs) and B-operand (V) agree on the
// 32x32x16 MFMA k-index mapping. RoPE q/k pair loads vectorized to single u32 (G13).
__global__ __launch_bounds__(256) void rope_vtrans(const unsigned short* __restrict__ qkvb,
                                                   unsigned short* __restrict__ Qb,
                                                   unsigned short* __restrict__ Kb,
                                                   unsigned short* __restrict__ Vtg) {
    const int st = blockIdx.x, h = blockIdx.y, b = blockIdx.z;
    const int tid = threadIdx.x;
    const int s0 = st * 64;

    // ---- RoPE on Q,K ----
    const int i  = tid & 31;
    const int r0 = tid >> 5;                   // 0..7
    const float inv_freq = exp2f(-(2.0f * (float)i / (float)DK) * log2f(50.0f));
    const float QSCALE = 0.125f * 1.44269504f; // 1/sqrt(dk) * log2(e)
#pragma unroll
    for (int pass = 0; pass < 8; ++pass) {
        const int s = s0 + r0 + pass * 8;
        const size_t in_base = ((size_t)(b * SEQ + s)) * (3 * D_MODEL) + h * DK + 2 * i;
        const unsigned int qin = *(const unsigned int*)&qkvb[in_base];
        const unsigned int kin = *(const unsigned int*)&qkvb[in_base + D_MODEL];
        const float q0 = bf2f((unsigned short)(qin & 0xFFFFu));
        const float q1 = bf2f((unsigned short)(qin >> 16));
        const float k0 = bf2f((unsigned short)(kin & 0xFFFFu));
        const float k1 = bf2f((unsigned short)(kin >> 16));
        float sn, cs;
        __sincosf((float)s * inv_freq, &sn, &cs);
        const size_t ob = (((size_t)(b * NHEADS + h)) * SEQ + s) * DK + 2 * i;
        const unsigned int qw = (unsigned int)f2bf((q0 * cs - q1 * sn) * QSCALE)
                              | ((unsigned int)f2bf((q1 * cs + q0 * sn) * QSCALE) << 16);
        const unsigned int kw = (unsigned int)f2bf(k0 * cs - k1 * sn)
                              | ((unsigned int)f2bf(k1 * cs + k0 * sn) << 16);
        *(unsigned int*)&Qb[ob] = qw;
        *(unsigned int*)&Kb[ob] = kw;
    }

    // ---- V transpose with sigma column permutation ----
    __shared__ unsigned short Lt[64][65];
    const int r = tid >> 3;                    // 0..31 (key within tile)
    const int c = (tid & 7) * 8;
    const size_t in_row = ((size_t)(b * SEQ + s0 + r)) * (3 * D_MODEL) + 2 * D_MODEL + h * DK + c;
    const ushort8 v0 = *(const ushort8*)&qkvb[in_row];
    const ushort8 v1 = *(const ushort8*)&qkvb[in_row + (size_t)32 * (3 * D_MODEL)];
    const int u0 = r, u1 = r + 32;
    const int kc0 = (u0 & 48) | (8 * ((u0 >> 2) & 1) + (u0 & 3) + 4 * ((u0 >> 3) & 1));
    const int kc1 = (u1 & 48) | (8 * ((u1 >> 2) & 1) + (u1 & 3) + 4 * ((u1 >> 3) & 1));
#pragma unroll
    for (int j = 0; j < 8; ++j) Lt[c + j][kc0] = v0[j];
#pragma unroll
    for (int j = 0; j < 8; ++j) Lt[c + j][kc1] = v1[j];
    __syncthreads();
    const size_t bh = (size_t)(b * NHEADS + h);
    ushort8 o0, o1;
#pragma unroll
    for (int j = 0; j < 8; ++j) { o0[j] = Lt[r][c + j]; o1[j] = Lt[r + 32][c + j]; }
    unsigned short* orow = Vtg + (bh * DK + r) * SEQ + s0 + c;   // r = d-row
    *(ushort8*)orow = o0;
    *(ushort8*)(orow + (size_t)32 * SEQ) = o1;
}

// ---------------- flash attention: QTILE=128, 8 waves, double-buffered K/V LDS ----
// Measured-best flash form (r3/r9/r10: 43.2-44.0us). Local optimum — deferred-PV
// 3-buf, 64qx32k LDS-reuse, and async gload_lds counted-vmcnt all measured WORSE
// (47.4/47.8/50.5). Do not re-attempt piecemeal grafts on this structure.
#define LDW 72

__global__ __launch_bounds__(512, 4) void flash_attn(const unsigned short* __restrict__ Qb,
                                                     const unsigned short* __restrict__ Kb,
                                                     const unsigned short* __restrict__ Vtg,
                                                     unsigned short* __restrict__ attnb) {
    const int tid  = threadIdx.x;
    const int wave = tid >> 6;
    const int lane = tid & 63;
    const int l31  = lane & 31;
    const int lh   = lane >> 5;               // lane half (k-group)
    const int mh2  = wave & 3;                // m-quarter (32 q rows of 128)
    const int kh   = wave >> 2;               // key-half (32 keys of 64)
    const int kb   = kh * 32;

    // XCD-grouping swizzle: 512 blocks, assume round-robin f%8 -> XCD
    const int f  = blockIdx.x + gridDim.x * (blockIdx.y + gridDim.y * blockIdx.z);
    const int w  = (f & 7) * 64 + (f >> 3);   // bijective (512 % 8 == 0)
    const int qt = w & 15;                    // 0..15 (tiles of 128 queries)
    const int h  = (w >> 4) & 15;
    const int b  = w >> 8;

    __shared__ __align__(16) unsigned char smem[36864];          // 2 x (Ks 9216 + Vt 9216)
    unsigned short (*Ks0)[LDW] = (unsigned short (*)[LDW])(smem);
    unsigned short (*Vt0)[LDW] = (unsigned short (*)[LDW])(smem +  9216);
    unsigned short (*Ks1)[LDW] = (unsigned short (*)[LDW])(smem + 18432);
    unsigned short (*Vt1)[LDW] = (unsigned short (*)[LDW])(smem + 27648);
    // epilogue overlays (staging dead): 128*68*4 + 2*128*4 = 35840 <= 36864
    float (*Ored)[68] = (float (*)[68])smem;
    float* lred0 = (float*)(smem + 34816);
    float* lred1 = lred0 + 128;

    const size_t bh = (size_t)(b * NHEADS + h);
    const unsigned short* Qg = Qb + (bh * SEQ + (size_t)qt * QTILE) * DK;
    const unsigned short* Kg = Kb + bh * SEQ * DK;
    const unsigned short* Vg = Vtg + bh * (size_t)DK * SEQ;

    // Q as B-operand: B[n=m=lane&31][k=lh*8+j]; frag t covers dk 16t..16t+15
    short8 qf[4];
#pragma unroll
    for (int t = 0; t < 4; ++t)
        qf[t] = *(const short8*)&Qg[(size_t)(mh2 * 32 + l31) * DK + t * 16 + lh * 8];

    // staging: 512 threads, each 1 short8 into Ks and 1 into Vt (64 rows x 64 cols)
    const int strow = tid >> 3;               // 0..63
    const int stcol = (tid & 7) * 8;
    const unsigned short* kg = &Kg[(size_t)strow * DK + stcol];
    const unsigned short* vg = &Vg[(size_t)strow * SEQ + stcol];

    short8 kr = *(const short8*)&kg[0];
    short8 vr = *(const short8*)&vg[0];

    floatx16 oacc[2];
    oacc[0] = (floatx16)(0.f);
    oacc[1] = (floatx16)(0.f);
    float lp = 0.f;                           // scalar l partial: query m = mh2*32+l31

    // diagonal tile for this wave: key global == q global  <=>  kt + kb == qt*128 + mh2*32
    const int diagkt = qt * QTILE + mh2 * 32 - kb;

    auto compute = [&](unsigned short (*Ks)[LDW], unsigned short (*Vt)[LDW], int kt) {
        // ---- S^T = K Q^T : C[row=key scatter][col=m=lane&31], 4 MFMAs ----
        floatx16 sc = (floatx16)(0.f);
        __builtin_amdgcn_s_setprio(1);
#pragma unroll
        for (int t = 0; t < 4; ++t) {
            const short8 kf = *(short8*)&Ks[kb + l31][t * 16 + lh * 8];
            sc = __builtin_amdgcn_mfma_f32_32x32x16_bf16(kf, qf[t], sc, 0, 0, 0);
        }
        __builtin_amdgcn_s_setprio(0);

        // ---- diagonal mask ----
        if (kt == diagkt) {
#pragma unroll
            for (int r = 0; r < 16; ++r) {
                const int key_loc = (r & 3) + 8 * (r >> 2) + 4 * lh;
                if (key_loc == l31) sc[r] = -1e30f;
            }
        }

        // ---- P = exp2(S^T): native v_exp_f32 + v_perm trunc pack; lp accumulates ----
        short8 pf0, pf1;
        {
            union { unsigned int u[4]; short8 s8; } a, c;
#pragma unroll
            for (int d = 0; d < 4; ++d) {
                const float e0 = __builtin_amdgcn_exp2f(sc[2 * d]);
                const float e1 = __builtin_amdgcn_exp2f(sc[2 * d + 1]);
                a.u[d] = __builtin_amdgcn_perm(fau(e1), fau(e0), 0x07060302u);
                const float f0 = __builtin_amdgcn_exp2f(sc[8 + 2 * d]);
                const float f1 = __builtin_amdgcn_exp2f(sc[8 + 2 * d + 1]);
                c.u[d] = __builtin_amdgcn_perm(fau(f1), fau(f0), 0x07060302u);
                lp += (e0 + e1) + (f0 + f1);
            }
            pf0 = a.s8;
            pf1 = c.s8;
        }

        // ---- O += P V  (V pre-permuted so k-indices align) ----
        __builtin_amdgcn_s_setprio(1);
#pragma unroll
        for (int nd = 0; nd < 2; ++nd) {
            const short8 vfa = *(short8*)&Vt[nd * 32 + l31][kb + lh * 8];        // keys 0..15
            const short8 vfb = *(short8*)&Vt[nd * 32 + l31][kb + 16 + lh * 8];   // keys 16..31
            oacc[nd] = __builtin_amdgcn_mfma_f32_32x32x16_bf16(pf0, vfa, oacc[nd], 0, 0, 0);
            oacc[nd] = __builtin_amdgcn_mfma_f32_32x32x16_bf16(pf1, vfb, oacc[nd], 0, 0, 0);
        }
        __builtin_amdgcn_s_setprio(0);
    };

    for (int kt = 0; kt < SEQ; kt += 128) {
        // ---- phase A: buffer 0, keys [kt, kt+64) ----
        *(short8*)&Ks0[strow][stcol] = kr;
        *(short8*)&Vt0[strow][stcol] = vr;
        __syncthreads();
        kr = *(const short8*)&kg[(size_t)(kt + 64) * DK];
        vr = *(const short8*)&vg[kt + 64];
        compute(Ks0, Vt0, kt);

        // ---- phase B: buffer 1, keys [kt+64, kt+128) ----
        *(short8*)&Ks1[strow][stcol] = kr;
        *(short8*)&Vt1[strow][stcol] = vr;
        __syncthreads();
        const int ktn = (kt + 128 < SEQ) ? kt + 128 : 0;
        kr = *(const short8*)&kg[(size_t)ktn * DK];
        vr = *(const short8*)&vg[ktn];
        compute(Ks1, Vt1, kt + 64);
    }

    // ---- l: combine the two lane-halves (same m, disjoint keys) ----
    const float lptot = lp + __shfl_xor(lp, 32, 64);

    // ---- cross-wave (key-half) reduction through LDS overlay ----
    __syncthreads();                          // staging buffers dead
    if (lh == 0) {
        if (kh == 0) lred0[mh2 * 32 + l31] = lptot;
        else         lred1[mh2 * 32 + l31] = lptot;
    }
    if (kh == 1) {
#pragma unroll
        for (int r = 0; r < 16; ++r) {
            const int m = mh2 * 32 + (r & 3) + 8 * (r >> 2) + 4 * lh;
            Ored[m][l31]      = oacc[0][r];
            Ored[m][32 + l31] = oacc[1][r];
        }
    }
    __syncthreads();
    if (kh == 0) {
        unsigned short* obase = attnb + ((size_t)b * SEQ + (size_t)qt * QTILE) * D_MODEL + h * DK;
        // 1.001953125 = 1/(1 - 2^-9): compensates mean truncation bias of bf16 P
        // (numerator uses trunc(P), denominator uses full-precision sums).
#pragma unroll
        for (int r = 0; r < 16; ++r) {
            const int m = mh2 * 32 + (r & 3) + 8 * (r >> 2) + 4 * lh;
            const float inv = 1.001953125f / (lred0[m] + lred1[m]);
            const float v0 = (oacc[0][r] + Ored[m][l31]) * inv;
            const float v1 = (oacc[1][r] + Ored[m][32 + l31]) * inv;
            obase[(size_t)m * D_MODEL + l31]      = f2bf(v0);
            obase[(size_t)m * D_MODEL + 32 + l31] = f2bf(v1);
        }
    }
}

extern "C" void kernel_launch(void* const* d_in, const int* in_sizes, int n_in,
                              void* d_out, int out_size, void* d_ws, size_t ws_size,
                              hipStream_t stream) {
    const float* x     = (const float*)d_in[0];
    const float* w_qkv = (const float*)d_in[1];
    const float* w_out = (const float*)d_in[2];
    const float* b_out = (const float*)d_in[3];
    float* out = (float*)d_out;

    const int M = BATCH * SEQ;                                   // 4096
    const size_t X_ELEMS    = (size_t)M * D_MODEL;
    const size_t WQKV_ELEMS = (size_t)3 * D_MODEL * D_MODEL;
    const size_t WOUT_ELEMS = (size_t)D_MODEL * D_MODEL;
    const size_t QKV_ELEMS  = (size_t)M * 3 * D_MODEL;
    const size_t HEAD_ELEMS = (size_t)BATCH * NHEADS * SEQ * DK;

    unsigned short* xb    = (unsigned short*)d_ws;
    unsigned short* wqkvb = xb + X_ELEMS;
    unsigned short* woutb = wqkvb + WQKV_ELEMS;
    unsigned short* qkvb  = woutb + WOUT_ELEMS;
    unsigned short* Qb    = qkvb + QKV_ELEMS;
    unsigned short* Kb    = Qb + HEAD_ELEMS;
    unsigned short* Vtg   = Kb + HEAD_ELEMS;                     // [B,H,64,S] sigma-permuted
    unsigned short* attnb = Vtg + HEAD_ELEMS;

    // 0) pack all inputs to bf16
    pack_all<<<(X8 + W8 + O8 + 255) / 256, 256, 0, stream>>>(x, w_qkv, w_out, xb, wqkvb, woutb);

    // 1) qkvb = xb @ wqkvb^T  (256x192 8-phase, snake B-reuse, super-tile swizzle)
    gemm_qkv_8ph<<<(QKV_M / 256) * (QKV_N / QKV_BN), 512, 0, stream>>>(xb, wqkvb, qkvb);

    // 2) RoPE pack + sigma-permuted V transpose
    {
        dim3 grid(SEQ / 64, NHEADS, BATCH);
        rope_vtrans<<<grid, 256, 0, stream>>>(qkvb, Qb, Kb, Vtg);
    }
    // 3) flash attention (QTILE=128, 8 waves, dbuf K/V — measured-best form)
    {
        dim3 grid(SEQ / QTILE, NHEADS, BATCH);
        flash_attn<<<grid, 512, 0, stream>>>(Qb, Kb, Vtg, attnb);
    }
    // 4) out = attnb @ woutb^T + b_out  (128^2 3-buffer, 1 barrier/K-tile, 256 blocks)
    gemm_out_3buf<<<(OUT_M / 128) * (OUT_N / 128), 512, 0, stream>>>(attnb, woutb, b_out, out);
}